// Round 9
// baseline (159.578 us; speedup 1.0000x reference)
//
#include <hip/hip_runtime.h>
#include <hip/hip_bf16.h>
#include <stdint.h>

typedef __bf16 bf16_t;
typedef __bf16 bf16x8 __attribute__((ext_vector_type(8)));
typedef float f32x4 __attribute__((ext_vector_type(4)));

#define MFMA_16x16x32(A, B, C) __builtin_amdgcn_mfma_f32_16x16x32_bf16((A), (B), (C), 0, 0, 0)

__device__ inline void gload_lds16(const bf16_t* g, bf16_t* lds) {
  auto* gp = (const __attribute__((address_space(1))) uint32_t*)(uintptr_t)g;
  auto* lp = (__attribute__((address_space(3))) uint32_t*)(uintptr_t)lds;
  __builtin_amdgcn_global_load_lds(gp, lp, 16, 0, 0);
}

// ---------- fp32 -> bf16 elementwise (small weights) ----------
__global__ void k_cvt(const float* __restrict__ in, bf16_t* __restrict__ out, int n) {
  int i = blockIdx.x * blockDim.x + threadIdx.x;
  if (i < n) out[i] = (bf16_t)in[i];
}

// ---------- transpose + cast: in [C][N] f32 -> out [N][C] bf16, per batch (z) ----------
__global__ __launch_bounds__(256)
void k_transpose_cast(const float* __restrict__ in, bf16_t* __restrict__ out, int C, int N) {
  __shared__ float tile[32][33];
  int b = blockIdx.z;
  const float* src = in + (size_t)b * C * N;
  bf16_t* dst = out + (size_t)b * C * N;
  int n0 = blockIdx.x * 32, c0 = blockIdx.y * 32;
  int tx = threadIdx.x, ty = threadIdx.y;
#pragma unroll
  for (int i = 0; i < 32; i += 8)
    tile[ty + i][tx] = src[(size_t)(c0 + ty + i) * N + (n0 + tx)];
  __syncthreads();
#pragma unroll
  for (int i = 0; i < 32; i += 8)
    dst[(size_t)(n0 + ty + i) * C + (c0 + tx)] = (bf16_t)tile[tx][ty + i];
}

// ---------- f_n -> fnT: read f32 [C][N], write bf16 [N][C], 64x64 tiles ----------
__global__ __launch_bounds__(256)
void k_fnT(const float* __restrict__ in, bf16_t* __restrict__ out_nc, int C, int N) {
  __shared__ float tile[64][65];
  const int b = blockIdx.z;
  const float* src = in + (size_t)b * C * N;
  const int n0 = blockIdx.x * 64, c0 = blockIdx.y * 64;
  const int t = threadIdx.x;
  const int cr = t >> 2;
  const int nc = (t & 3) * 16;
  {
    const float* srow = src + (size_t)(c0 + cr) * N + n0 + nc;
#pragma unroll
    for (int q = 0; q < 4; ++q) {
      float4 v = *(const float4*)(srow + q * 4);
      tile[cr][nc + q * 4 + 0] = v.x; tile[cr][nc + q * 4 + 1] = v.y;
      tile[cr][nc + q * 4 + 2] = v.z; tile[cr][nc + q * 4 + 3] = v.w;
    }
  }
  __syncthreads();
  {
    const int nr = t >> 2;
    const int cc = (t & 3) * 16;
    bf16_t on[16];
#pragma unroll
    for (int q = 0; q < 16; ++q) on[q] = (bf16_t)tile[cc + q][nr];
    bf16_t* dst = out_nc + (size_t)b * (size_t)N * C + (size_t)(n0 + nr) * C + c0 + cc;
    *(uint4*)(dst) = *(uint4*)(on);
    *(uint4*)(dst + 8) = *(uint4*)(on + 8);
  }
}

// ---------- H partials, 256x256 tile, 8 waves, f32-direct, split-K=16 ----------
// Hp[b*16+ks][c'][c]; BK=32 (8 steps), dbuf, one barrier/step, 2 blocks/CU.
__global__ __launch_bounds__(512, 2)
void k_gram256(const float* __restrict__ A, const float* __restrict__ B,
               bf16_t* __restrict__ Cp) {
  const int raw = blockIdx.x;              // 512 blocks
  const int b = raw & 7, idx = raw >> 3;   // XCD-affine: xcd = batch
  const int mt = idx & 1, nt = (idx >> 1) & 1, ks = idx >> 2;  // ks 0..15
  const float* Ab = A + (size_t)b * 512 * 4096;
  const float* Bb = B + (size_t)b * 512 * 4096;
  const int bm = mt * 256, bn = nt * 256;
  const int kbeg = ks * 256;               // 8 steps of BK=32

  const int tid = threadIdx.x;
  const int wave = tid >> 6, lane = tid & 63;
  const int l15 = lane & 15, l4 = lane >> 4;
  const int wm = (wave >> 2) * 128, wn = (wave & 3) * 64;
  const int rsw = (l15 >> 1) & 3;

  __shared__ bf16_t As[2][256 * 32];
  __shared__ bf16_t Bs[2][256 * 32];

  f32x4 acc[8][4] = {};

  const int rho = tid >> 1, h = tid & 1;
  const int sw = (rho >> 1) & 3;
  const int wo0 = rho * 32 + (((2 * h) ^ sw) * 8);
  const int wo1 = rho * 32 + (((2 * h + 1) ^ sw) * 8);
  const float* ga = Ab + (size_t)(bm + rho) * 4096 + kbeg + h * 16;
  const float* gb = Bb + (size_t)(bn + rho) * 4096 + kbeg + h * 16;

  float4 ra[4], rb[4];
#pragma unroll
  for (int q = 0; q < 4; ++q) {
    ra[q] = *(const float4*)(ga + q * 4);
    rb[q] = *(const float4*)(gb + q * 4);
  }

  int cur = 0;
  for (int i = 0; i < 8; ++i) {
    bf16_t ta[16], tb[16];
#pragma unroll
    for (int q = 0; q < 4; ++q) {
      ta[q * 4 + 0] = (bf16_t)ra[q].x; ta[q * 4 + 1] = (bf16_t)ra[q].y;
      ta[q * 4 + 2] = (bf16_t)ra[q].z; ta[q * 4 + 3] = (bf16_t)ra[q].w;
      tb[q * 4 + 0] = (bf16_t)rb[q].x; tb[q * 4 + 1] = (bf16_t)rb[q].y;
      tb[q * 4 + 2] = (bf16_t)rb[q].z; tb[q * 4 + 3] = (bf16_t)rb[q].w;
    }
    *(uint4*)(&As[cur][wo0]) = *(uint4*)(ta);
    *(uint4*)(&As[cur][wo1]) = *(uint4*)(ta + 8);
    *(uint4*)(&Bs[cur][wo0]) = *(uint4*)(tb);
    *(uint4*)(&Bs[cur][wo1]) = *(uint4*)(tb + 8);
    if (i + 1 < 8) {
      const float* na = ga + (i + 1) * 32;
      const float* nb = gb + (i + 1) * 32;
#pragma unroll
      for (int q = 0; q < 4; ++q) {
        ra[q] = *(const float4*)(na + q * 4);
        rb[q] = *(const float4*)(nb + q * 4);
      }
    }
    __syncthreads();
    bf16x8 bfr[4];
#pragma unroll
    for (int n = 0; n < 4; ++n)
      bfr[n] = *(const bf16x8*)(&Bs[cur][(wn + n * 16 + l15) * 32 + ((l4 ^ rsw) * 8)]);
#pragma unroll
    for (int m = 0; m < 8; ++m) {
      bf16x8 af = *(const bf16x8*)(&As[cur][(wm + m * 16 + l15) * 32 + ((l4 ^ rsw) * 8)]);
#pragma unroll
      for (int n = 0; n < 4; ++n)
        acc[m][n] = MFMA_16x16x32(af, bfr[n], acc[m][n]);
    }
    cur ^= 1;
  }

  bf16_t* Cb = Cp + (size_t)(b * 16 + ks) * 262144;
#pragma unroll
  for (int m = 0; m < 8; ++m) {
    const int row0 = bm + wm + m * 16 + l4 * 4;
#pragma unroll
    for (int n = 0; n < 4; ++n) {
      const int col = bn + wn + n * 16 + l15;
#pragma unroll
      for (int j = 0; j < 4; ++j)
        Cb[(size_t)(row0 + j) * 512 + col] = (bf16_t)acc[m][n][j];
    }
  }
}

// ---------- y GEMM, 256x128 tile, 8 waves (4m x 2n), 2 blocks/CU ----------
// y[b][o][n] = sum_c W2[b][o][c] * fnT[b][n][c] + bias[o]
__global__ __launch_bounds__(512, 2)
void k_y256(const bf16_t* __restrict__ A, const bf16_t* __restrict__ B,
            float* __restrict__ C, const float* __restrict__ bias) {
  const int raw = blockIdx.x;              // 512 blocks
  const int b = raw & 7, c = raw >> 3;     // XCD-affine: xcd = batch
  const int bm = (c & 1) * 256, bn = (c >> 1) * 128;   // M=512, N=4096
  A += (size_t)b * 262144;
  B += (size_t)b * 4096 * 512;
  C += (size_t)b * 512 * 4096;

  const int tid = threadIdx.x;
  const int wave = tid >> 6, lane = tid & 63;
  const int l15 = lane & 15, l4 = lane >> 4;
  const int wm = (wave >> 1) * 64, wn = (wave & 1) * 64;
  const int rsw = (l15 >> 1) & 3;

  __shared__ bf16_t As[2][256 * 32];
  __shared__ bf16_t Bs[2][128 * 32];

  f32x4 acc[4][4] = {};

  // gload_lds: lane l -> dest row base+(l>>2), phys chunk l&3.
  // Source pre-swizzle: logical chunk = (l&3) ^ ((l>>3)&3)  [= phys ^ ((row>>1)&3)].
  const int lrow = lane >> 2;
  const int lch = (lane & 3) ^ ((lane >> 3) & 3);
  const bf16_t* srcA = A + (size_t)(bm + wave * 32 + lrow) * 512 + lch * 8;
  const bf16_t* srcB = B + (size_t)(bn + wave * 16 + lrow) * 512 + lch * 8;
  bf16_t* dstA = &As[0][wave * 32 * 32];
  bf16_t* dstB = &Bs[0][wave * 16 * 32];
  const int bufA = 256 * 32, bufB = 128 * 32;

  auto stage = [&](int buf, int k0) {
    gload_lds16(srcA + k0,            dstA + buf * bufA);
    gload_lds16(srcA + 16 * 512 + k0, dstA + buf * bufA + 512);
    gload_lds16(srcB + k0,            dstB + buf * bufB);
  };

  stage(0, 0);
  __syncthreads();

  int cur = 0;
  for (int i = 0; i < 16; ++i) {
    if (i + 1 < 16) stage(cur ^ 1, (i + 1) * 32);
    bf16x8 af[4], bfr[4];
#pragma unroll
    for (int n = 0; n < 4; ++n)
      bfr[n] = *(const bf16x8*)(&Bs[cur][(wn + n * 16 + l15) * 32 + ((l4 ^ rsw) * 8)]);
#pragma unroll
    for (int m = 0; m < 4; ++m)
      af[m] = *(const bf16x8*)(&As[cur][(wm + m * 16 + l15) * 32 + ((l4 ^ rsw) * 8)]);
#pragma unroll
    for (int m = 0; m < 4; ++m)
#pragma unroll
      for (int n = 0; n < 4; ++n)
        acc[m][n] = MFMA_16x16x32(af[m], bfr[n], acc[m][n]);
    __syncthreads();   // drains vmcnt -> next buf staged; all reads of cur done
    cur ^= 1;
  }

#pragma unroll
  for (int m = 0; m < 4; ++m) {
    const int row0 = bm + wm + m * 16 + l4 * 4;
#pragma unroll
    for (int n = 0; n < 4; ++n) {
      const int col = bn + wn + n * 16 + l15;
#pragma unroll
      for (int j = 0; j < 4; ++j)
        C[(size_t)(row0 + j) * 4096 + col] = acc[m][n][j] + bias[row0 + j];
    }
  }
}

// ---------- reduce 16 bf16 split-K partials -> bf16 ----------
__global__ __launch_bounds__(256)
void k_reduce16(const bf16_t* __restrict__ p, bf16_t* __restrict__ out) {
  int i = blockIdx.x * blockDim.x + threadIdx.x;  // 262144 threads
  int b = i >> 15;
  int e8 = (i & 32767) * 8;
  const bf16_t* pb = p + (size_t)b * 16 * 262144 + e8;
  float s[8] = {};
#pragma unroll
  for (int ks = 0; ks < 16; ++ks) {
    bf16x8 v = *(const bf16x8*)(pb + (size_t)ks * 262144);
#pragma unroll
    for (int j = 0; j < 8; ++j) s[j] += (float)v[j];
  }
  bf16x8 o;
#pragma unroll
  for (int j = 0; j < 8; ++j) o[j] = (bf16_t)s[j];
  *(bf16x8*)(out + (size_t)b * 262144 + e8) = o;
}

// ---------- small GEMM C[M][N] = A[M][K] B[N][K]^T, 128x128, dbuf (bf16 out) ----------
__global__ __launch_bounds__(256)
void k_gemm_bt(const bf16_t* __restrict__ A, const bf16_t* __restrict__ B,
               bf16_t* __restrict__ Cv, int M, int N, int K,
               long long sA, long long sB, long long sC) {
  const int zb = blockIdx.z;
  A += (size_t)zb * sA;
  B += (size_t)zb * sB;

  const int tid = threadIdx.x;
  const int wave = tid >> 6, lane = tid & 63;
  const int l15 = lane & 15, l4 = lane >> 4;
  const int bm = blockIdx.y * 128, bn = blockIdx.x * 128;
  const int wm = (wave >> 1) * 64, wn = (wave & 1) * 64;

  __shared__ bf16_t As[2][128 * 32];
  __shared__ bf16_t Bs[2][128 * 32];

  f32x4 acc[4][4] = {};

  const int lrow = lane >> 2;
  const int lchunk = (lane & 3) * 8;
  const int ra = wave * 16 + lrow;

  auto stage = [&](int buf, int k0) {
    gload_lds16(&A[(size_t)(bm + ra) * K + k0 + lchunk],      &As[buf][(wave * 16) * 32]);
    gload_lds16(&A[(size_t)(bm + 64 + ra) * K + k0 + lchunk], &As[buf][(64 + wave * 16) * 32]);
    gload_lds16(&B[(size_t)(bn + ra) * K + k0 + lchunk],      &Bs[buf][(wave * 16) * 32]);
    gload_lds16(&B[(size_t)(bn + 64 + ra) * K + k0 + lchunk], &Bs[buf][(64 + wave * 16) * 32]);
  };

  const int nsteps = K / 32;
  stage(0, 0);
  __syncthreads();

  for (int i = 0; i < nsteps; ++i) {
    const int cur = i & 1;
    if (i + 1 < nsteps) stage(cur ^ 1, (i + 1) * 32);
    bf16x8 af[4], bfr[4];
#pragma unroll
    for (int m = 0; m < 4; ++m)
      af[m] = *(const bf16x8*)(&As[cur][(wm + m * 16 + l15) * 32 + l4 * 8]);
#pragma unroll
    for (int n = 0; n < 4; ++n)
      bfr[n] = *(const bf16x8*)(&Bs[cur][(wn + n * 16 + l15) * 32 + l4 * 8]);
#pragma unroll
    for (int m = 0; m < 4; ++m)
#pragma unroll
      for (int n = 0; n < 4; ++n)
        acc[m][n] = MFMA_16x16x32(af[m], bfr[n], acc[m][n]);
    __syncthreads();
  }

#pragma unroll
  for (int m = 0; m < 4; ++m) {
    const int row0 = bm + wm + m * 16 + l4 * 4;
#pragma unroll
    for (int n = 0; n < 4; ++n) {
      const int col = bn + wn + n * 16 + l15;
#pragma unroll
      for (int j = 0; j < 4; ++j)
        (Cv + (size_t)zb * sC)[(size_t)(row0 + j) * N + col] = (bf16_t)acc[m][n][j];
    }
  }
}

// ---------- dots + softmax: one block per (b,h) ----------
__global__ __launch_bounds__(256)
void k_dots_softmax(const bf16_t* __restrict__ T1, const bf16_t* __restrict__ wk,
                    bf16_t* __restrict__ attn) {
  const int bh = blockIdx.x;
  const bf16_t* qh = T1 + (size_t)(bh >> 3) * 262144 + (size_t)(bh & 7) * 64 * 512;
  const bf16_t* kh = wk + (size_t)(bh & 7) * 64 * 512;
  const int tid = threadIdx.x;
  const int wave = tid >> 6, lane = tid & 63;
  const int l15 = lane & 15, l4 = lane >> 4;
  const int wm = (wave >> 1) * 32, wn = (wave & 1) * 32;

  f32x4 acc[2][2] = {};
#pragma unroll 2
  for (int k0 = 0; k0 < 512; k0 += 32) {
    bf16x8 af[2], bfr[2];
#pragma unroll
    for (int m = 0; m < 2; ++m)
      af[m] = *(const bf16x8*)(&qh[(size_t)(wm + m * 16 + l15) * 512 + k0 + l4 * 8]);
#pragma unroll
    for (int n = 0; n < 2; ++n)
      bfr[n] = *(const bf16x8*)(&kh[(size_t)(wn + n * 16 + l15) * 512 + k0 + l4 * 8]);
#pragma unroll
    for (int m = 0; m < 2; ++m)
#pragma unroll
      for (int n = 0; n < 2; ++n)
        acc[m][n] = MFMA_16x16x32(af[m], bfr[n], acc[m][n]);
  }

  __shared__ float S[64][65];
  const float scale = 0.125f;
#pragma unroll
  for (int m = 0; m < 2; ++m)
#pragma unroll
    for (int n = 0; n < 2; ++n)
#pragma unroll
      for (int j = 0; j < 4; ++j)
        S[wm + m * 16 + l4 * 4 + j][wn + n * 16 + l15] = acc[m][n][j] * scale;
  __syncthreads();

  const int r = tid >> 2, seg = (tid & 3) * 16;
  float vals[16];
  float mx = -1e30f;
#pragma unroll
  for (int c = 0; c < 16; ++c) { vals[c] = S[r][seg + c]; mx = fmaxf(mx, vals[c]); }
  mx = fmaxf(mx, __shfl_xor(mx, 1));
  mx = fmaxf(mx, __shfl_xor(mx, 2));
  float sum = 0.f;
#pragma unroll
  for (int c = 0; c < 16; ++c) { vals[c] = __expf(vals[c] - mx); sum += vals[c]; }
  sum += __shfl_xor(sum, 1);
  sum += __shfl_xor(sum, 2);
  const float inv = 1.0f / sum;
  bf16_t* arow = attn + (size_t)bh * 64 * 64 + (size_t)r * 64 + seg;
#pragma unroll
  for (int c = 0; c < 16; ++c) arow[c] = (bf16_t)(vals[c] * inv);
}

// ---------- WvEffT[b][c][h*64+i] = sum_j WvT[h][c][j] * attn[bh][i][j] ----------
__global__ __launch_bounds__(256)
void k_wveff(const bf16_t* __restrict__ wvT, const bf16_t* __restrict__ attn,
             bf16_t* __restrict__ wveffT) {
  const int bh = blockIdx.y;
  const int b = bh >> 3, h = bh & 7;
  const int tid = threadIdx.x;
  const int wave = tid >> 6, lane = tid & 63;
  const int l15 = lane & 15, l4 = lane >> 4;
  const bf16_t* av = wvT + (size_t)h * 512 * 64;
  const bf16_t* ab = attn + (size_t)bh * 64 * 64;
  bf16_t* ob = wveffT + (size_t)b * 262144 + (size_t)h * 64;
  const int cm0 = blockIdx.x * 128;
  const int wm = (wave >> 1) * 64, wn = (wave & 1) * 32;

  f32x4 acc[4][2] = {};
#pragma unroll
  for (int ks = 0; ks < 2; ++ks) {
    const int k0 = ks * 32;
    bf16x8 af[4], bfr[2];
#pragma unroll
    for (int m = 0; m < 4; ++m)
      af[m] = *(const bf16x8*)(&av[(size_t)(cm0 + wm + m * 16 + l15) * 64 + k0 + l4 * 8]);
#pragma unroll
    for (int n = 0; n < 2; ++n)
      bfr[n] = *(const bf16x8*)(&ab[(wn + n * 16 + l15) * 64 + k0 + l4 * 8]);
#pragma unroll
    for (int m = 0; m < 4; ++m)
#pragma unroll
      for (int n = 0; n < 2; ++n)
        acc[m][n] = MFMA_16x16x32(af[m], bfr[n], acc[m][n]);
  }
#pragma unroll
  for (int m = 0; m < 4; ++m)
#pragma unroll
    for (int n = 0; n < 2; ++n)
#pragma unroll
      for (int j = 0; j < 4; ++j)
        ob[(size_t)(cm0 + wm + m * 16 + l4 * 4 + j) * 512 + wn + n * 16 + l15] =
            (bf16_t)acc[m][n][j];
}

extern "C" void kernel_launch(void* const* d_in, const int* in_sizes, int n_in,
                              void* d_out, int out_size, void* d_ws, size_t ws_size,
                              hipStream_t stream) {
  const float* f_m  = (const float*)d_in[0];
  const float* f_n  = (const float*)d_in[1];
  const float* Wq   = (const float*)d_in[2];
  const float* Wkv  = (const float*)d_in[3];
  const float* Wout = (const float*)d_in[4];
  const float* bout = (const float*)d_in[5];
  float* y = (float*)d_out;

  const size_t ACT = (size_t)8 * 4096 * 512;
  const size_t SQ  = (size_t)512 * 512;
  char* p = (char*)d_ws;
  bf16_t* wq_b    = (bf16_t*)p; p += SQ * 2;
  bf16_t* wk_b    = (bf16_t*)p; p += SQ * 2;
  bf16_t* wout_b  = (bf16_t*)p; p += SQ * 2;
  bf16_t* wvT     = (bf16_t*)p; p += SQ * 2;               // [h][c][64]
  bf16_t* attnw   = (bf16_t*)p; p += (size_t)64 * 64 * 64 * 2;
  bf16_t* Hb      = (bf16_t*)p; p += (size_t)8 * SQ * 2;   // [b][c'][c]
  bf16_t* T1      = (bf16_t*)p; p += (size_t)8 * SQ * 2;   // [b][hi][c']
  bf16_t* wveffT  = (bf16_t*)p; p += (size_t)8 * SQ * 2;   // [b][c][hi]
  bf16_t* W2      = (bf16_t*)p; p += (size_t)8 * SQ * 2;   // [b][o][c]
  bf16_t* Hp16    = (bf16_t*)p; p += (size_t)128 * SQ * 2; // bf16 split-16 partials
  bf16_t* fnT     = (bf16_t*)p; p += ACT * 2;              // [b][n][c]

  // weights
  k_cvt<<<dim3((int)(SQ / 256)), 256, 0, stream>>>(Wq, wq_b, (int)SQ);
  k_cvt<<<dim3((int)(SQ / 256)), 256, 0, stream>>>(Wkv, wk_b, (int)SQ);
  k_cvt<<<dim3((int)(SQ / 256)), 256, 0, stream>>>(Wout, wout_b, (int)SQ);
  k_transpose_cast<<<dim3(16, 2, 8), dim3(32, 8), 0, stream>>>(Wkv + SQ, wvT, 64, 512);

  // fnT (f_n then L3-warm for k_gram256)
  k_fnT<<<dim3(64, 8, 8), 256, 0, stream>>>(f_n, fnT, 512, 4096);

  // H from f32 inputs, 256^2 tiles, split-K=16, 2 blocks/CU
  k_gram256<<<dim3(512), 512, 0, stream>>>(f_n, f_m, Hp16);
  k_reduce16<<<dim3(1024), 256, 0, stream>>>(Hp16, Hb);

  // T1[b][hi][c'] = sum_c Wq[hi][c] H[b][c'][c]
  k_gemm_bt<<<dim3(4, 4, 8), 256, 0, stream>>>(wq_b, Hb, T1, 512, 512, 512,
                                               0, (long long)SQ, (long long)SQ);
  // dots + softmax -> attn
  k_dots_softmax<<<dim3(64), 256, 0, stream>>>(T1, wk_b, attnw);
  // WvEffT[b][c][hi]
  k_wveff<<<dim3(4, 64), 256, 0, stream>>>(wvT, attnw, wveffT);
  // W2[b][o][c] = sum_hi Wout[o][hi] WvEffT[b][c][hi]
  k_gemm_bt<<<dim3(4, 4, 8), 256, 0, stream>>>(wout_b, wveffT, W2, 512, 512, 512,
                                               0, (long long)SQ, (long long)SQ);
  // y[b][o][n] = sum_c W2[b][o][c] fnT[b][n][c] + bout[o], 256x128 tiles, 2/CU
  k_y256<<<dim3(512), 512, 0, stream>>>(W2, fnT, y, bout);
}

// Round 10
// 135.731 us; speedup vs baseline: 1.1757x; 1.1757x over previous
//
#include <hip/hip_runtime.h>
#include <hip/hip_bf16.h>
#include <stdint.h>

typedef __bf16 bf16_t;
typedef __bf16 bf16x8 __attribute__((ext_vector_type(8)));
typedef float f32x4 __attribute__((ext_vector_type(4)));

#define MFMA_16x16x32(A, B, C) __builtin_amdgcn_mfma_f32_16x16x32_bf16((A), (B), (C), 0, 0, 0)

__device__ inline void gload_lds16(const bf16_t* g, bf16_t* lds) {
  auto* gp = (const __attribute__((address_space(1))) uint32_t*)(uintptr_t)g;
  auto* lp = (__attribute__((address_space(3))) uint32_t*)(uintptr_t)lds;
  __builtin_amdgcn_global_load_lds(gp, lp, 16, 0, 0);
}

// ---------- fused fp32 -> bf16 for the three square weight mats ----------
__global__ __launch_bounds__(256)
void k_cvt3(const float* __restrict__ a, const float* __restrict__ b,
            const float* __restrict__ c, bf16_t* __restrict__ oa,
            bf16_t* __restrict__ ob, bf16_t* __restrict__ oc) {
  int i = blockIdx.x * blockDim.x + threadIdx.x;   // 196608 threads, 4 elems each
  int region = i >> 16;                            // 65536 threads per 262144-elem mat
  int e = (i & 65535) * 4;
  const float* src = region == 0 ? a : (region == 1 ? b : c);
  bf16_t* dst = region == 0 ? oa : (region == 1 ? ob : oc);
  float4 v = *(const float4*)(src + e);
  bf16_t o[4] = {(bf16_t)v.x, (bf16_t)v.y, (bf16_t)v.z, (bf16_t)v.w};
  *(uint2*)(dst + e) = *(uint2*)o;
}

// ---------- transpose + cast: in [C][N] f32 -> out [N][C] bf16, per batch (z) ----------
__global__ __launch_bounds__(256)
void k_transpose_cast(const float* __restrict__ in, bf16_t* __restrict__ out, int C, int N) {
  __shared__ float tile[32][33];
  int b = blockIdx.z;
  const float* src = in + (size_t)b * C * N;
  bf16_t* dst = out + (size_t)b * C * N;
  int n0 = blockIdx.x * 32, c0 = blockIdx.y * 32;
  int tx = threadIdx.x, ty = threadIdx.y;
#pragma unroll
  for (int i = 0; i < 32; i += 8)
    tile[ty + i][tx] = src[(size_t)(c0 + ty + i) * N + (n0 + tx)];
  __syncthreads();
#pragma unroll
  for (int i = 0; i < 32; i += 8)
    dst[(size_t)(n0 + ty + i) * C + (c0 + tx)] = (bf16_t)tile[tx][ty + i];
}

// ---------- f_n -> fnT: read f32 [C][N], write bf16 [N][C], 64x64 tiles ----------
__global__ __launch_bounds__(256)
void k_fnT(const float* __restrict__ in, bf16_t* __restrict__ out_nc, int C, int N) {
  __shared__ float tile[64][65];
  const int b = blockIdx.z;
  const float* src = in + (size_t)b * C * N;
  const int n0 = blockIdx.x * 64, c0 = blockIdx.y * 64;
  const int t = threadIdx.x;
  const int cr = t >> 2;
  const int nc = (t & 3) * 16;
  {
    const float* srow = src + (size_t)(c0 + cr) * N + n0 + nc;
#pragma unroll
    for (int q = 0; q < 4; ++q) {
      float4 v = *(const float4*)(srow + q * 4);
      tile[cr][nc + q * 4 + 0] = v.x; tile[cr][nc + q * 4 + 1] = v.y;
      tile[cr][nc + q * 4 + 2] = v.z; tile[cr][nc + q * 4 + 3] = v.w;
    }
  }
  __syncthreads();
  {
    const int nr = t >> 2;
    const int cc = (t & 3) * 16;
    bf16_t on[16];
#pragma unroll
    for (int q = 0; q < 16; ++q) on[q] = (bf16_t)tile[cc + q][nr];
    bf16_t* dst = out_nc + (size_t)b * (size_t)N * C + (size_t)(n0 + nr) * C + c0 + cc;
    *(uint4*)(dst) = *(uint4*)(on);
    *(uint4*)(dst + 8) = *(uint4*)(on + 8);
  }
}

// ---------- H partials, 256x256 tile, 8 waves, f32-direct, split-K=8 (round-8 cfg) ----------
__global__ __launch_bounds__(512, 2)
void k_gram256(const float* __restrict__ A, const float* __restrict__ B,
               bf16_t* __restrict__ Cp) {
  const int raw = blockIdx.x;              // 256 blocks
  const int xcd = raw & 7, idx = raw >> 3; // XCD-affine: xcd = batch
  const int mt = idx & 1, nt = (idx >> 1) & 1, ks = idx >> 2;  // ks 0..7
  const int b = xcd;
  const float* Ab = A + (size_t)b * 512 * 4096;
  const float* Bb = B + (size_t)b * 512 * 4096;
  const int bm = mt * 256, bn = nt * 256;
  const int kbeg = ks * 512;               // 16 steps of BK=32

  const int tid = threadIdx.x;
  const int wave = tid >> 6, lane = tid & 63;
  const int l15 = lane & 15, l4 = lane >> 4;
  const int wm = (wave >> 2) * 128, wn = (wave & 3) * 64;
  const int rsw = (l15 >> 1) & 3;

  __shared__ bf16_t As[2][256 * 32];
  __shared__ bf16_t Bs[2][256 * 32];

  f32x4 acc[8][4] = {};

  const int rho = tid >> 1, h = tid & 1;
  const int sw = (rho >> 1) & 3;
  const int wo0 = rho * 32 + (((2 * h) ^ sw) * 8);
  const int wo1 = rho * 32 + (((2 * h + 1) ^ sw) * 8);
  const float* ga = Ab + (size_t)(bm + rho) * 4096 + kbeg + h * 16;
  const float* gb = Bb + (size_t)(bn + rho) * 4096 + kbeg + h * 16;

  float4 ra[4], rb[4];
#pragma unroll
  for (int q = 0; q < 4; ++q) {
    ra[q] = *(const float4*)(ga + q * 4);
    rb[q] = *(const float4*)(gb + q * 4);
  }

  int cur = 0;
  for (int i = 0; i < 16; ++i) {
    bf16_t ta[16], tb[16];
#pragma unroll
    for (int q = 0; q < 4; ++q) {
      ta[q * 4 + 0] = (bf16_t)ra[q].x; ta[q * 4 + 1] = (bf16_t)ra[q].y;
      ta[q * 4 + 2] = (bf16_t)ra[q].z; ta[q * 4 + 3] = (bf16_t)ra[q].w;
      tb[q * 4 + 0] = (bf16_t)rb[q].x; tb[q * 4 + 1] = (bf16_t)rb[q].y;
      tb[q * 4 + 2] = (bf16_t)rb[q].z; tb[q * 4 + 3] = (bf16_t)rb[q].w;
    }
    *(uint4*)(&As[cur][wo0]) = *(uint4*)(ta);
    *(uint4*)(&As[cur][wo1]) = *(uint4*)(ta + 8);
    *(uint4*)(&Bs[cur][wo0]) = *(uint4*)(tb);
    *(uint4*)(&Bs[cur][wo1]) = *(uint4*)(tb + 8);
    if (i + 1 < 16) {
      const float* na = ga + (i + 1) * 32;
      const float* nb = gb + (i + 1) * 32;
#pragma unroll
      for (int q = 0; q < 4; ++q) {
        ra[q] = *(const float4*)(na + q * 4);
        rb[q] = *(const float4*)(nb + q * 4);
      }
    }
    __syncthreads();
    bf16x8 bfr[4];
#pragma unroll
    for (int n = 0; n < 4; ++n)
      bfr[n] = *(const bf16x8*)(&Bs[cur][(wn + n * 16 + l15) * 32 + ((l4 ^ rsw) * 8)]);
#pragma unroll
    for (int m = 0; m < 8; ++m) {
      bf16x8 af = *(const bf16x8*)(&As[cur][(wm + m * 16 + l15) * 32 + ((l4 ^ rsw) * 8)]);
#pragma unroll
      for (int n = 0; n < 4; ++n)
        acc[m][n] = MFMA_16x16x32(af, bfr[n], acc[m][n]);
    }
    cur ^= 1;
  }

  bf16_t* Cb = Cp + (size_t)(b * 8 + ks) * 262144;
#pragma unroll
  for (int m = 0; m < 8; ++m) {
    const int row0 = bm + wm + m * 16 + l4 * 4;
#pragma unroll
    for (int n = 0; n < 4; ++n) {
      const int col = bn + wn + n * 16 + l15;
#pragma unroll
      for (int j = 0; j < 4; ++j)
        Cb[(size_t)(row0 + j) * 512 + col] = (bf16_t)acc[m][n][j];
    }
  }
}

// ---------- y GEMM, 256x256 tile, 8 waves, gload_lds w/ pre-swizzled source (round-8) ----------
__global__ __launch_bounds__(512, 2)
void k_y256(const bf16_t* __restrict__ A, const bf16_t* __restrict__ B,
            float* __restrict__ C, const float* __restrict__ bias) {
  const int raw = blockIdx.x;              // 256 blocks
  const int b = raw & 7, c = raw >> 3;     // XCD-affine: xcd = batch
  const int bm = (c & 1) * 256, bn = (c >> 1) * 256;   // M=512, N=4096
  A += (size_t)b * 262144;
  B += (size_t)b * 4096 * 512;
  C += (size_t)b * 512 * 4096;

  const int tid = threadIdx.x;
  const int wave = tid >> 6, lane = tid & 63;
  const int l15 = lane & 15, l4 = lane >> 4;
  const int wm = (wave >> 2) * 128, wn = (wave & 3) * 64;
  const int rsw = (l15 >> 1) & 3;

  __shared__ bf16_t As[2][256 * 32];
  __shared__ bf16_t Bs[2][256 * 32];

  f32x4 acc[8][4] = {};

  const int lrow = lane >> 2;
  const int lch = (lane & 3) ^ ((lane >> 3) & 3);
  const bf16_t* srcA = A + (size_t)(bm + wave * 32 + lrow) * 512 + lch * 8;
  const bf16_t* srcB = B + (size_t)(bn + wave * 32 + lrow) * 512 + lch * 8;
  bf16_t* dstA = &As[0][wave * 32 * 32];
  bf16_t* dstB = &Bs[0][wave * 32 * 32];
  const int bufoff = 256 * 32;

  auto stage = [&](int buf, int k0) {
    gload_lds16(srcA + k0,            dstA + buf * bufoff);
    gload_lds16(srcA + 16 * 512 + k0, dstA + buf * bufoff + 512);
    gload_lds16(srcB + k0,            dstB + buf * bufoff);
    gload_lds16(srcB + 16 * 512 + k0, dstB + buf * bufoff + 512);
  };

  stage(0, 0);
  __syncthreads();

  int cur = 0;
  for (int i = 0; i < 16; ++i) {
    if (i + 1 < 16) stage(cur ^ 1, (i + 1) * 32);
    bf16x8 bfr[4];
#pragma unroll
    for (int n = 0; n < 4; ++n)
      bfr[n] = *(const bf16x8*)(&Bs[cur][(wn + n * 16 + l15) * 32 + ((l4 ^ rsw) * 8)]);
#pragma unroll
    for (int m = 0; m < 8; ++m) {
      bf16x8 af = *(const bf16x8*)(&As[cur][(wm + m * 16 + l15) * 32 + ((l4 ^ rsw) * 8)]);
#pragma unroll
      for (int n = 0; n < 4; ++n)
        acc[m][n] = MFMA_16x16x32(af, bfr[n], acc[m][n]);
    }
    __syncthreads();
    cur ^= 1;
  }

#pragma unroll
  for (int m = 0; m < 8; ++m) {
    const int row0 = bm + wm + m * 16 + l4 * 4;
#pragma unroll
    for (int n = 0; n < 4; ++n) {
      const int col = bn + wn + n * 16 + l15;
#pragma unroll
      for (int j = 0; j < 4; ++j)
        C[(size_t)(row0 + j) * 4096 + col] = acc[m][n][j] + bias[row0 + j];
    }
  }
}

// ---------- reduce 8 bf16 split-K partials -> bf16 ----------
__global__ __launch_bounds__(256)
void k_reduce8(const bf16_t* __restrict__ p, bf16_t* __restrict__ out) {
  int i = blockIdx.x * blockDim.x + threadIdx.x;  // 262144 threads
  int b = i >> 15;
  int e8 = (i & 32767) * 8;
  const bf16_t* pb = p + (size_t)b * 8 * 262144 + e8;
  float s[8] = {};
#pragma unroll
  for (int ks = 0; ks < 8; ++ks) {
    bf16x8 v = *(const bf16x8*)(pb + (size_t)ks * 262144);
#pragma unroll
    for (int j = 0; j < 8; ++j) s[j] += (float)v[j];
  }
  bf16x8 o;
#pragma unroll
  for (int j = 0; j < 8; ++j) o[j] = (bf16_t)s[j];
  *(bf16x8*)(out + (size_t)b * 262144 + e8) = o;
}

// ---------- small GEMM C[M][N] = A[M][K] B[N][K]^T, 128x128, dbuf (bf16 out) ----------
__global__ __launch_bounds__(256)
void k_gemm_bt(const bf16_t* __restrict__ A, const bf16_t* __restrict__ B,
               bf16_t* __restrict__ Cv, int M, int N, int K,
               long long sA, long long sB, long long sC) {
  const int zb = blockIdx.z;
  A += (size_t)zb * sA;
  B += (size_t)zb * sB;

  const int tid = threadIdx.x;
  const int wave = tid >> 6, lane = tid & 63;
  const int l15 = lane & 15, l4 = lane >> 4;
  const int bm = blockIdx.y * 128, bn = blockIdx.x * 128;
  const int wm = (wave >> 1) * 64, wn = (wave & 1) * 64;

  __shared__ bf16_t As[2][128 * 32];
  __shared__ bf16_t Bs[2][128 * 32];

  f32x4 acc[4][4] = {};

  const int lrow = lane >> 2;
  const int lchunk = (lane & 3) * 8;
  const int ra = wave * 16 + lrow;

  auto stage = [&](int buf, int k0) {
    gload_lds16(&A[(size_t)(bm + ra) * K + k0 + lchunk],      &As[buf][(wave * 16) * 32]);
    gload_lds16(&A[(size_t)(bm + 64 + ra) * K + k0 + lchunk], &As[buf][(64 + wave * 16) * 32]);
    gload_lds16(&B[(size_t)(bn + ra) * K + k0 + lchunk],      &Bs[buf][(wave * 16) * 32]);
    gload_lds16(&B[(size_t)(bn + 64 + ra) * K + k0 + lchunk], &Bs[buf][(64 + wave * 16) * 32]);
  };

  const int nsteps = K / 32;
  stage(0, 0);
  __syncthreads();

  for (int i = 0; i < nsteps; ++i) {
    const int cur = i & 1;
    if (i + 1 < nsteps) stage(cur ^ 1, (i + 1) * 32);
    bf16x8 af[4], bfr[4];
#pragma unroll
    for (int m = 0; m < 4; ++m)
      af[m] = *(const bf16x8*)(&As[cur][(wm + m * 16 + l15) * 32 + l4 * 8]);
#pragma unroll
    for (int n = 0; n < 4; ++n)
      bfr[n] = *(const bf16x8*)(&Bs[cur][(wn + n * 16 + l15) * 32 + l4 * 8]);
#pragma unroll
    for (int m = 0; m < 4; ++m)
#pragma unroll
      for (int n = 0; n < 4; ++n)
        acc[m][n] = MFMA_16x16x32(af[m], bfr[n], acc[m][n]);
    __syncthreads();
  }

#pragma unroll
  for (int m = 0; m < 4; ++m) {
    const int row0 = bm + wm + m * 16 + l4 * 4;
#pragma unroll
    for (int n = 0; n < 4; ++n) {
      const int col = bn + wn + n * 16 + l15;
#pragma unroll
      for (int j = 0; j < 4; ++j)
        (Cv + (size_t)zb * sC)[(size_t)(row0 + j) * N + col] = (bf16_t)acc[m][n][j];
    }
  }
}

// ---------- fused dots + softmax + wveff: one block per (b,h) ----------
// Phase 1: dots[i][j] = scale * <T1[b][h*64+i][:], wk[h*64+j][:]>; softmax -> P (LDS).
// Phase 2: wveffT[b][c][h*64+i] = sum_j wvT[h][c][j] * P[i][j], looped over c-tiles.
__global__ __launch_bounds__(256)
void k_dots_wveff(const bf16_t* __restrict__ T1, const bf16_t* __restrict__ wk,
                  const bf16_t* __restrict__ wvT, bf16_t* __restrict__ wveffT) {
  const int bh = blockIdx.x;
  const int b = bh >> 3, hh = bh & 7;
  const bf16_t* qh = T1 + (size_t)b * 262144 + (size_t)hh * 64 * 512;
  const bf16_t* kh = wk + (size_t)hh * 64 * 512;
  const int tid = threadIdx.x;
  const int wave = tid >> 6, lane = tid & 63;
  const int l15 = lane & 15, l4 = lane >> 4;

  __shared__ float S[64][65];
  __shared__ bf16_t P[64][72];   // attn weights, padded (row stride 36 banks)

  {  // ---- phase 1: dots ----
    const int wm = (wave >> 1) * 32, wn = (wave & 1) * 32;
    f32x4 acc[2][2] = {};
#pragma unroll 2
    for (int k0 = 0; k0 < 512; k0 += 32) {
      bf16x8 af[2], bfr[2];
#pragma unroll
      for (int m = 0; m < 2; ++m)
        af[m] = *(const bf16x8*)(&qh[(size_t)(wm + m * 16 + l15) * 512 + k0 + l4 * 8]);
#pragma unroll
      for (int n = 0; n < 2; ++n)
        bfr[n] = *(const bf16x8*)(&kh[(size_t)(wn + n * 16 + l15) * 512 + k0 + l4 * 8]);
#pragma unroll
      for (int m = 0; m < 2; ++m)
#pragma unroll
        for (int n = 0; n < 2; ++n)
          acc[m][n] = MFMA_16x16x32(af[m], bfr[n], acc[m][n]);
    }
    const float scale = 0.125f;
#pragma unroll
    for (int m = 0; m < 2; ++m)
#pragma unroll
      for (int n = 0; n < 2; ++n)
#pragma unroll
        for (int j = 0; j < 4; ++j)
          S[wm + m * 16 + l4 * 4 + j][wn + n * 16 + l15] = acc[m][n][j] * scale;
  }
  __syncthreads();

  {  // ---- softmax: 4 threads per row -> P ----
    const int r = tid >> 2, seg = (tid & 3) * 16;
    float vals[16];
    float mx = -1e30f;
#pragma unroll
    for (int c = 0; c < 16; ++c) { vals[c] = S[r][seg + c]; mx = fmaxf(mx, vals[c]); }
    mx = fmaxf(mx, __shfl_xor(mx, 1));
    mx = fmaxf(mx, __shfl_xor(mx, 2));
    float sum = 0.f;
#pragma unroll
    for (int c = 0; c < 16; ++c) { vals[c] = __expf(vals[c] - mx); sum += vals[c]; }
    sum += __shfl_xor(sum, 1);
    sum += __shfl_xor(sum, 2);
    const float inv = 1.0f / sum;
    bf16_t pr[16];
#pragma unroll
    for (int c = 0; c < 16; ++c) pr[c] = (bf16_t)(vals[c] * inv);
    *(uint4*)(&P[r][seg]) = *(uint4*)(pr);
    *(uint4*)(&P[r][seg + 8]) = *(uint4*)(pr + 8);
  }
  __syncthreads();

  {  // ---- phase 2: wveff over 4 c-tiles of 128 ----
    const bf16_t* av = wvT + (size_t)hh * 512 * 64;
    bf16_t* ob = wveffT + (size_t)b * 262144 + (size_t)hh * 64;
    const int wm = (wave >> 1) * 64, wn = (wave & 1) * 32;
    for (int cm0 = 0; cm0 < 512; cm0 += 128) {
      f32x4 acc[4][2] = {};
#pragma unroll
      for (int ks = 0; ks < 2; ++ks) {
        const int k0 = ks * 32;
        bf16x8 af[4], bfr[2];
#pragma unroll
        for (int m = 0; m < 4; ++m)
          af[m] = *(const bf16x8*)(&av[(size_t)(cm0 + wm + m * 16 + l15) * 64 + k0 + l4 * 8]);
#pragma unroll
        for (int n = 0; n < 2; ++n)
          bfr[n] = *(const bf16x8*)(&P[wn + n * 16 + l15][k0 + l4 * 8]);
#pragma unroll
        for (int m = 0; m < 4; ++m)
#pragma unroll
          for (int n = 0; n < 2; ++n)
            acc[m][n] = MFMA_16x16x32(af[m], bfr[n], acc[m][n]);
      }
#pragma unroll
      for (int m = 0; m < 4; ++m)
#pragma unroll
        for (int n = 0; n < 2; ++n)
#pragma unroll
          for (int j = 0; j < 4; ++j)
            ob[(size_t)(cm0 + wm + m * 16 + l4 * 4 + j) * 512 + wn + n * 16 + l15] =
                (bf16_t)acc[m][n][j];
    }
  }
}

extern "C" void kernel_launch(void* const* d_in, const int* in_sizes, int n_in,
                              void* d_out, int out_size, void* d_ws, size_t ws_size,
                              hipStream_t stream) {
  const float* f_m  = (const float*)d_in[0];
  const float* f_n  = (const float*)d_in[1];
  const float* Wq   = (const float*)d_in[2];
  const float* Wkv  = (const float*)d_in[3];
  const float* Wout = (const float*)d_in[4];
  const float* bout = (const float*)d_in[5];
  float* y = (float*)d_out;

  const size_t ACT = (size_t)8 * 4096 * 512;
  const size_t SQ  = (size_t)512 * 512;
  char* p = (char*)d_ws;
  bf16_t* wq_b    = (bf16_t*)p; p += SQ * 2;
  bf16_t* wk_b    = (bf16_t*)p; p += SQ * 2;
  bf16_t* wout_b  = (bf16_t*)p; p += SQ * 2;
  bf16_t* wvT     = (bf16_t*)p; p += SQ * 2;               // [h][c][64]
  bf16_t* Hb      = (bf16_t*)p; p += (size_t)8 * SQ * 2;   // [b][c'][c]
  bf16_t* T1      = (bf16_t*)p; p += (size_t)8 * SQ * 2;   // [b][hi][c']
  bf16_t* wveffT  = (bf16_t*)p; p += (size_t)8 * SQ * 2;   // [b][c][hi]
  bf16_t* W2      = (bf16_t*)p; p += (size_t)8 * SQ * 2;   // [b][o][c]
  bf16_t* Hp8     = (bf16_t*)p; p += (size_t)64 * SQ * 2;  // bf16 split-8 partials
  bf16_t* fnT     = (bf16_t*)p; p += ACT * 2;              // [b][n][c]

  // weights: 3 cvts in one launch + Wv transpose
  k_cvt3<<<dim3(768), 256, 0, stream>>>(Wq, Wkv, Wout, wq_b, wk_b, wout_b);
  k_transpose_cast<<<dim3(16, 2, 8), dim3(32, 8), 0, stream>>>(Wkv + SQ, wvT, 64, 512);

  // fnT (f_n then L3-warm for k_gram256)
  k_fnT<<<dim3(64, 8, 8), 256, 0, stream>>>(f_n, fnT, 512, 4096);

  // H from f32 inputs, 256^2 tiles, split-K=8 (round-8 verified config)
  k_gram256<<<dim3(256), 512, 0, stream>>>(f_n, f_m, Hp8);
  k_reduce8<<<dim3(1024), 256, 0, stream>>>(Hp8, Hb);

  // T1[b][hi][c'] = sum_c Wq[hi][c] H[b][c'][c]
  k_gemm_bt<<<dim3(4, 4, 8), 256, 0, stream>>>(wq_b, Hb, T1, 512, 512, 512,
                                               0, (long long)SQ, (long long)SQ);
  // dots + softmax + wveff fused
  k_dots_wveff<<<dim3(64), 256, 0, stream>>>(T1, wk_b, wvT, wveffT);
  // W2[b][o][c] = sum_hi Wout[o][hi] WvEffT[b][c][hi]
  k_gemm_bt<<<dim3(4, 4, 8), 256, 0, stream>>>(wout_b, wveffT, W2, 512, 512, 512,
                                               0, (long long)SQ, (long long)SQ);
  // y[b][o][n] = sum_c W2[b][o][c] fnT[b][n][c] + bout[o], 256^2 tiles
  k_y256<<<dim3(256), 512, 0, stream>>>(W2, fnT, y, bout);
}

// Round 11
// 127.576 us; speedup vs baseline: 1.2508x; 1.0639x over previous
//
#include <hip/hip_runtime.h>
#include <hip/hip_bf16.h>
#include <stdint.h>

typedef __bf16 bf16_t;
typedef __bf16 bf16x8 __attribute__((ext_vector_type(8)));
typedef float f32x4 __attribute__((ext_vector_type(4)));

#define MFMA_16x16x32(A, B, C) __builtin_amdgcn_mfma_f32_16x16x32_bf16((A), (B), (C), 0, 0, 0)

__device__ inline void gload_lds16(const bf16_t* g, bf16_t* lds) {
  auto* gp = (const __attribute__((address_space(1))) uint32_t*)(uintptr_t)g;
  auto* lp = (__attribute__((address_space(3))) uint32_t*)(uintptr_t)lds;
  __builtin_amdgcn_global_load_lds(gp, lp, 16, 0, 0);
}

// ================== fused front: gram (L3-bound) || fnT+cvt3+wvT (HBM-bound) ==========
// Role by blockIdx: [0,256) gram; [256,2304) fnT (2 tiles/block); [2304,2688) cvt3;
// [2688,2816) wvT transpose (2 tiles/block).  512 threads.  LDS = union (64 KB max).
__global__ __launch_bounds__(512, 2)
void k_front(const float* __restrict__ f_m, const float* __restrict__ f_n,
             const float* __restrict__ Wq, const float* __restrict__ Wkv,
             const float* __restrict__ Wout,
             bf16_t* __restrict__ Hp, bf16_t* __restrict__ fnT,
             bf16_t* __restrict__ wq_b, bf16_t* __restrict__ wk_b,
             bf16_t* __restrict__ wout_b, bf16_t* __restrict__ wvT) {
  __shared__ __align__(16) char ldsbuf[65536];
  const int bid = blockIdx.x;
  const int tid = threadIdx.x;

  if (bid < 256) {
    // ---------------- gram role (round-8/10 verified body) ----------------
    const int xcd = bid & 7, idx = bid >> 3;
    const int mt = idx & 1, nt = (idx >> 1) & 1, ks = idx >> 2;  // ks 0..7
    const int b = xcd;
    const float* Ab = f_n + (size_t)b * 512 * 4096;
    const float* Bb = f_m + (size_t)b * 512 * 4096;
    const int bm = mt * 256, bn = nt * 256;
    const int kbeg = ks * 512;               // 16 steps of BK=32

    const int wave = tid >> 6, lane = tid & 63;
    const int l15 = lane & 15, l4 = lane >> 4;
    const int wm = (wave >> 2) * 128, wn = (wave & 3) * 64;
    const int rsw = (l15 >> 1) & 3;

    bf16_t* As0 = (bf16_t*)ldsbuf;           // [2][8192]
    bf16_t* Bs0 = As0 + 16384;               // [2][8192]

    f32x4 acc[8][4] = {};

    const int rho = tid >> 1, h = tid & 1;
    const int sw = (rho >> 1) & 3;
    const int wo0 = rho * 32 + (((2 * h) ^ sw) * 8);
    const int wo1 = rho * 32 + (((2 * h + 1) ^ sw) * 8);
    const float* ga = Ab + (size_t)(bm + rho) * 4096 + kbeg + h * 16;
    const float* gb = Bb + (size_t)(bn + rho) * 4096 + kbeg + h * 16;

    float4 ra[4], rb[4];
#pragma unroll
    for (int q = 0; q < 4; ++q) {
      ra[q] = *(const float4*)(ga + q * 4);
      rb[q] = *(const float4*)(gb + q * 4);
    }

    int cur = 0;
    for (int i = 0; i < 16; ++i) {
      bf16_t* As = As0 + cur * 8192;
      bf16_t* Bs = Bs0 + cur * 8192;
      bf16_t ta[16], tb[16];
#pragma unroll
      for (int q = 0; q < 4; ++q) {
        ta[q * 4 + 0] = (bf16_t)ra[q].x; ta[q * 4 + 1] = (bf16_t)ra[q].y;
        ta[q * 4 + 2] = (bf16_t)ra[q].z; ta[q * 4 + 3] = (bf16_t)ra[q].w;
        tb[q * 4 + 0] = (bf16_t)rb[q].x; tb[q * 4 + 1] = (bf16_t)rb[q].y;
        tb[q * 4 + 2] = (bf16_t)rb[q].z; tb[q * 4 + 3] = (bf16_t)rb[q].w;
      }
      *(uint4*)(&As[wo0]) = *(uint4*)(ta);
      *(uint4*)(&As[wo1]) = *(uint4*)(ta + 8);
      *(uint4*)(&Bs[wo0]) = *(uint4*)(tb);
      *(uint4*)(&Bs[wo1]) = *(uint4*)(tb + 8);
      if (i + 1 < 16) {
        const float* na = ga + (i + 1) * 32;
        const float* nb = gb + (i + 1) * 32;
#pragma unroll
        for (int q = 0; q < 4; ++q) {
          ra[q] = *(const float4*)(na + q * 4);
          rb[q] = *(const float4*)(nb + q * 4);
        }
      }
      __syncthreads();
      bf16x8 bfr[4];
#pragma unroll
      for (int n = 0; n < 4; ++n)
        bfr[n] = *(const bf16x8*)(&Bs[(wn + n * 16 + l15) * 32 + ((l4 ^ rsw) * 8)]);
#pragma unroll
      for (int m = 0; m < 8; ++m) {
        bf16x8 af = *(const bf16x8*)(&As[(wm + m * 16 + l15) * 32 + ((l4 ^ rsw) * 8)]);
#pragma unroll
        for (int n = 0; n < 4; ++n)
          acc[m][n] = MFMA_16x16x32(af, bfr[n], acc[m][n]);
      }
      cur ^= 1;
    }

    bf16_t* Cb = Hp + (size_t)(b * 8 + ks) * 262144;
#pragma unroll
    for (int m = 0; m < 8; ++m) {
      const int row0 = bm + wm + m * 16 + l4 * 4;
#pragma unroll
      for (int n = 0; n < 4; ++n) {
        const int col = bn + wn + n * 16 + l15;
#pragma unroll
        for (int j = 0; j < 4; ++j)
          Cb[(size_t)(row0 + j) * 512 + col] = (bf16_t)acc[m][n][j];
      }
    }
  } else if (bid < 2304) {
    // ---------------- fnT role: two 64x64 tiles (round-10 verified body) ----------
    const int half = tid >> 8;               // 0 or 1
    const int t = tid & 255;
    const int tileIdx = (bid - 256) * 2 + half;   // 0..4095
    const int ntile = tileIdx & 63, ctile = (tileIdx >> 6) & 7, b = tileIdx >> 9;
    const int C = 512, N = 4096;
    const float* src = f_n + (size_t)b * C * N;
    const int n0 = ntile * 64, c0 = ctile * 64;
    float* tile = (float*)ldsbuf + half * (64 * 65);   // [64][65]

    const int cr = t >> 2;
    const int nc = (t & 3) * 16;
    {
      const float* srow = src + (size_t)(c0 + cr) * N + n0 + nc;
#pragma unroll
      for (int q = 0; q < 4; ++q) {
        float4 v = *(const float4*)(srow + q * 4);
        tile[cr * 65 + nc + q * 4 + 0] = v.x; tile[cr * 65 + nc + q * 4 + 1] = v.y;
        tile[cr * 65 + nc + q * 4 + 2] = v.z; tile[cr * 65 + nc + q * 4 + 3] = v.w;
      }
    }
    __syncthreads();
    {
      const int nr = t >> 2;
      const int cc = (t & 3) * 16;
      bf16_t on[16];
#pragma unroll
      for (int q = 0; q < 16; ++q) on[q] = (bf16_t)tile[(cc + q) * 65 + nr];
      bf16_t* dst = fnT + (size_t)b * (size_t)N * C + (size_t)(n0 + nr) * C + c0 + cc;
      *(uint4*)(dst) = *(uint4*)(on);
      *(uint4*)(dst + 8) = *(uint4*)(on + 8);
    }
  } else if (bid < 2688) {
    // ---------------- cvt3 role: 4 f32->bf16 per thread across 3 weight mats -------
    int i = (bid - 2304) * 512 + tid;        // 196608 threads
    int region = i >> 16;
    int e = (i & 65535) * 4;
    const float* src = region == 0 ? Wq : (region == 1 ? Wkv : Wout);
    bf16_t* dst = region == 0 ? wq_b : (region == 1 ? wk_b : wout_b);
    float4 v = *(const float4*)(src + e);
    bf16_t o[4] = {(bf16_t)v.x, (bf16_t)v.y, (bf16_t)v.z, (bf16_t)v.w};
    *(uint2*)(dst + e) = *(uint2*)o;
  } else {
    // ---------------- wvT role: two 32x32 transpose tiles (Wv -> [h][c][64]) -------
    const int half = tid >> 8;
    const int t = tid & 255;
    const int tileIdx = (bid - 2688) * 2 + half;  // 0..255
    const int x = tileIdx & 15, yy = (tileIdx >> 4) & 1, z = tileIdx >> 5;
    const int C = 64, N = 512;
    const float* src = Wkv + (size_t)512 * 512 + (size_t)z * C * N;
    bf16_t* dst = wvT + (size_t)z * C * N;
    const int n0 = x * 32, c0 = yy * 32;
    float* tile = (float*)ldsbuf + half * (32 * 33);
    const int tx = t & 31, ty = (t >> 5) & 7;
#pragma unroll
    for (int i = 0; i < 32; i += 8)
      tile[(ty + i) * 33 + tx] = src[(size_t)(c0 + ty + i) * N + (n0 + tx)];
    __syncthreads();
#pragma unroll
    for (int i = 0; i < 32; i += 8)
      dst[(size_t)(n0 + ty + i) * C + (c0 + tx)] = (bf16_t)tile[tx * 33 + ty + i];
  }
}

// ---------- reduce 8 bf16 split-K partials -> bf16 ----------
__global__ __launch_bounds__(256)
void k_reduce8(const bf16_t* __restrict__ p, bf16_t* __restrict__ out) {
  int i = blockIdx.x * blockDim.x + threadIdx.x;  // 262144 threads
  int b = i >> 15;
  int e8 = (i & 32767) * 8;
  const bf16_t* pb = p + (size_t)b * 8 * 262144 + e8;
  float s[8] = {};
#pragma unroll
  for (int ks = 0; ks < 8; ++ks) {
    bf16x8 v = *(const bf16x8*)(pb + (size_t)ks * 262144);
#pragma unroll
    for (int j = 0; j < 8; ++j) s[j] += (float)v[j];
  }
  bf16x8 o;
#pragma unroll
  for (int j = 0; j < 8; ++j) o[j] = (bf16_t)s[j];
  *(bf16x8*)(out + (size_t)b * 262144 + e8) = o;
}

// ---------- small GEMM C[M][N] = A[M][K] B[N][K]^T, 128x128, dbuf (bf16 out) ----------
__global__ __launch_bounds__(256)
void k_gemm_bt(const bf16_t* __restrict__ A, const bf16_t* __restrict__ B,
               bf16_t* __restrict__ Cv, int M, int N, int K,
               long long sA, long long sB, long long sC) {
  const int zb = blockIdx.z;
  A += (size_t)zb * sA;
  B += (size_t)zb * sB;

  const int tid = threadIdx.x;
  const int wave = tid >> 6, lane = tid & 63;
  const int l15 = lane & 15, l4 = lane >> 4;
  const int bm = blockIdx.y * 128, bn = blockIdx.x * 128;
  const int wm = (wave >> 1) * 64, wn = (wave & 1) * 64;

  __shared__ bf16_t As[2][128 * 32];
  __shared__ bf16_t Bs[2][128 * 32];

  f32x4 acc[4][4] = {};

  const int lrow = lane >> 2;
  const int lchunk = (lane & 3) * 8;
  const int ra = wave * 16 + lrow;

  auto stage = [&](int buf, int k0) {
    gload_lds16(&A[(size_t)(bm + ra) * K + k0 + lchunk],      &As[buf][(wave * 16) * 32]);
    gload_lds16(&A[(size_t)(bm + 64 + ra) * K + k0 + lchunk], &As[buf][(64 + wave * 16) * 32]);
    gload_lds16(&B[(size_t)(bn + ra) * K + k0 + lchunk],      &Bs[buf][(wave * 16) * 32]);
    gload_lds16(&B[(size_t)(bn + 64 + ra) * K + k0 + lchunk], &Bs[buf][(64 + wave * 16) * 32]);
  };

  const int nsteps = K / 32;
  stage(0, 0);
  __syncthreads();

  for (int i = 0; i < nsteps; ++i) {
    const int cur = i & 1;
    if (i + 1 < nsteps) stage(cur ^ 1, (i + 1) * 32);
    bf16x8 af[4], bfr[4];
#pragma unroll
    for (int m = 0; m < 4; ++m)
      af[m] = *(const bf16x8*)(&As[cur][(wm + m * 16 + l15) * 32 + l4 * 8]);
#pragma unroll
    for (int n = 0; n < 4; ++n)
      bfr[n] = *(const bf16x8*)(&Bs[cur][(wn + n * 16 + l15) * 32 + l4 * 8]);
#pragma unroll
    for (int m = 0; m < 4; ++m)
#pragma unroll
      for (int n = 0; n < 4; ++n)
        acc[m][n] = MFMA_16x16x32(af[m], bfr[n], acc[m][n]);
    __syncthreads();
  }

#pragma unroll
  for (int m = 0; m < 4; ++m) {
    const int row0 = bm + wm + m * 16 + l4 * 4;
#pragma unroll
    for (int n = 0; n < 4; ++n) {
      const int col = bn + wn + n * 16 + l15;
#pragma unroll
      for (int j = 0; j < 4; ++j)
        (Cv + (size_t)zb * sC)[(size_t)(row0 + j) * N + col] = (bf16_t)acc[m][n][j];
    }
  }
}

// ---------- fused dots + softmax + wveff: one block per (b,h) ----------
__global__ __launch_bounds__(256)
void k_dots_wveff(const bf16_t* __restrict__ T1, const bf16_t* __restrict__ wk,
                  const bf16_t* __restrict__ wvT, bf16_t* __restrict__ wveffT) {
  const int bh = blockIdx.x;
  const int b = bh >> 3, hh = bh & 7;
  const bf16_t* qh = T1 + (size_t)b * 262144 + (size_t)hh * 64 * 512;
  const bf16_t* kh = wk + (size_t)hh * 64 * 512;
  const int tid = threadIdx.x;
  const int wave = tid >> 6, lane = tid & 63;
  const int l15 = lane & 15, l4 = lane >> 4;

  __shared__ float S[64][65];
  __shared__ bf16_t P[64][72];

  {
    const int wm = (wave >> 1) * 32, wn = (wave & 1) * 32;
    f32x4 acc[2][2] = {};
#pragma unroll 2
    for (int k0 = 0; k0 < 512; k0 += 32) {
      bf16x8 af[2], bfr[2];
#pragma unroll
      for (int m = 0; m < 2; ++m)
        af[m] = *(const bf16x8*)(&qh[(size_t)(wm + m * 16 + l15) * 512 + k0 + l4 * 8]);
#pragma unroll
      for (int n = 0; n < 2; ++n)
        bfr[n] = *(const bf16x8*)(&kh[(size_t)(wn + n * 16 + l15) * 512 + k0 + l4 * 8]);
#pragma unroll
      for (int m = 0; m < 2; ++m)
#pragma unroll
        for (int n = 0; n < 2; ++n)
          acc[m][n] = MFMA_16x16x32(af[m], bfr[n], acc[m][n]);
    }
    const float scale = 0.125f;
#pragma unroll
    for (int m = 0; m < 2; ++m)
#pragma unroll
      for (int n = 0; n < 2; ++n)
#pragma unroll
        for (int j = 0; j < 4; ++j)
          S[wm + m * 16 + l4 * 4 + j][wn + n * 16 + l15] = acc[m][n][j] * scale;
  }
  __syncthreads();

  {
    const int r = tid >> 2, seg = (tid & 3) * 16;
    float vals[16];
    float mx = -1e30f;
#pragma unroll
    for (int c = 0; c < 16; ++c) { vals[c] = S[r][seg + c]; mx = fmaxf(mx, vals[c]); }
    mx = fmaxf(mx, __shfl_xor(mx, 1));
    mx = fmaxf(mx, __shfl_xor(mx, 2));
    float sum = 0.f;
#pragma unroll
    for (int c = 0; c < 16; ++c) { vals[c] = __expf(vals[c] - mx); sum += vals[c]; }
    sum += __shfl_xor(sum, 1);
    sum += __shfl_xor(sum, 2);
    const float inv = 1.0f / sum;
    bf16_t pr[16];
#pragma unroll
    for (int c = 0; c < 16; ++c) pr[c] = (bf16_t)(vals[c] * inv);
    *(uint4*)(&P[r][seg]) = *(uint4*)(pr);
    *(uint4*)(&P[r][seg + 8]) = *(uint4*)(pr + 8);
  }
  __syncthreads();

  {
    const bf16_t* av = wvT + (size_t)hh * 512 * 64;
    bf16_t* ob = wveffT + (size_t)b * 262144 + (size_t)hh * 64;
    const int wm = (wave >> 1) * 64, wn = (wave & 1) * 32;
    for (int cm0 = 0; cm0 < 512; cm0 += 128) {
      f32x4 acc[4][2] = {};
#pragma unroll
      for (int ks = 0; ks < 2; ++ks) {
        const int k0 = ks * 32;
        bf16x8 af[4], bfr[2];
#pragma unroll
        for (int m = 0; m < 4; ++m)
          af[m] = *(const bf16x8*)(&av[(size_t)(cm0 + wm + m * 16 + l15) * 64 + k0 + l4 * 8]);
#pragma unroll
        for (int n = 0; n < 2; ++n)
          bfr[n] = *(const bf16x8*)(&P[wn + n * 16 + l15][k0 + l4 * 8]);
#pragma unroll
        for (int m = 0; m < 4; ++m)
#pragma unroll
          for (int n = 0; n < 2; ++n)
            acc[m][n] = MFMA_16x16x32(af[m], bfr[n], acc[m][n]);
      }
#pragma unroll
      for (int m = 0; m < 4; ++m)
#pragma unroll
        for (int n = 0; n < 2; ++n)
#pragma unroll
          for (int j = 0; j < 4; ++j)
            ob[(size_t)(cm0 + wm + m * 16 + l4 * 4 + j) * 512 + wn + n * 16 + l15] =
                (bf16_t)acc[m][n][j];
    }
  }
}

// ---------- y GEMM, 256x256 tile, 8 waves, gload_lds w/ pre-swizzled source ----------
__global__ __launch_bounds__(512, 2)
void k_y256(const bf16_t* __restrict__ A, const bf16_t* __restrict__ B,
            float* __restrict__ C, const float* __restrict__ bias) {
  const int raw = blockIdx.x;              // 256 blocks
  const int b = raw & 7, c = raw >> 3;     // XCD-affine: xcd = batch
  const int bm = (c & 1) * 256, bn = (c >> 1) * 256;   // M=512, N=4096
  A += (size_t)b * 262144;
  B += (size_t)b * 4096 * 512;
  C += (size_t)b * 512 * 4096;

  const int tid = threadIdx.x;
  const int wave = tid >> 6, lane = tid & 63;
  const int l15 = lane & 15, l4 = lane >> 4;
  const int wm = (wave >> 2) * 128, wn = (wave & 3) * 64;
  const int rsw = (l15 >> 1) & 3;

  __shared__ bf16_t As[2][256 * 32];
  __shared__ bf16_t Bs[2][256 * 32];

  f32x4 acc[8][4] = {};

  const int lrow = lane >> 2;
  const int lch = (lane & 3) ^ ((lane >> 3) & 3);
  const bf16_t* srcA = A + (size_t)(bm + wave * 32 + lrow) * 512 + lch * 8;
  const bf16_t* srcB = B + (size_t)(bn + wave * 32 + lrow) * 512 + lch * 8;
  bf16_t* dstA = &As[0][wave * 32 * 32];
  bf16_t* dstB = &Bs[0][wave * 32 * 32];
  const int bufoff = 256 * 32;

  auto stage = [&](int buf, int k0) {
    gload_lds16(srcA + k0,            dstA + buf * bufoff);
    gload_lds16(srcA + 16 * 512 + k0, dstA + buf * bufoff + 512);
    gload_lds16(srcB + k0,            dstB + buf * bufoff);
    gload_lds16(srcB + 16 * 512 + k0, dstB + buf * bufoff + 512);
  };

  stage(0, 0);
  __syncthreads();

  int cur = 0;
  for (int i = 0; i < 16; ++i) {
    if (i + 1 < 16) stage(cur ^ 1, (i + 1) * 32);
    bf16x8 bfr[4];
#pragma unroll
    for (int n = 0; n < 4; ++n)
      bfr[n] = *(const bf16x8*)(&Bs[cur][(wn + n * 16 + l15) * 32 + ((l4 ^ rsw) * 8)]);
#pragma unroll
    for (int m = 0; m < 8; ++m) {
      bf16x8 af = *(const bf16x8*)(&As[cur][(wm + m * 16 + l15) * 32 + ((l4 ^ rsw) * 8)]);
#pragma unroll
      for (int n = 0; n < 4; ++n)
        acc[m][n] = MFMA_16x16x32(af, bfr[n], acc[m][n]);
    }
    __syncthreads();
    cur ^= 1;
  }

#pragma unroll
  for (int m = 0; m < 8; ++m) {
    const int row0 = bm + wm + m * 16 + l4 * 4;
#pragma unroll
    for (int n = 0; n < 4; ++n) {
      const int col = bn + wn + n * 16 + l15;
#pragma unroll
      for (int j = 0; j < 4; ++j)
        C[(size_t)(row0 + j) * 4096 + col] = acc[m][n][j] + bias[row0 + j];
    }
  }
}

extern "C" void kernel_launch(void* const* d_in, const int* in_sizes, int n_in,
                              void* d_out, int out_size, void* d_ws, size_t ws_size,
                              hipStream_t stream) {
  const float* f_m  = (const float*)d_in[0];
  const float* f_n  = (const float*)d_in[1];
  const float* Wq   = (const float*)d_in[2];
  const float* Wkv  = (const float*)d_in[3];
  const float* Wout = (const float*)d_in[4];
  const float* bout = (const float*)d_in[5];
  float* y = (float*)d_out;

  const size_t ACT = (size_t)8 * 4096 * 512;
  const size_t SQ  = (size_t)512 * 512;
  char* p = (char*)d_ws;
  bf16_t* wq_b    = (bf16_t*)p; p += SQ * 2;
  bf16_t* wk_b    = (bf16_t*)p; p += SQ * 2;
  bf16_t* wout_b  = (bf16_t*)p; p += SQ * 2;
  bf16_t* wvT     = (bf16_t*)p; p += SQ * 2;               // [h][c][64]
  bf16_t* Hb      = (bf16_t*)p; p += (size_t)8 * SQ * 2;   // [b][c'][c]
  bf16_t* T1      = (bf16_t*)p; p += (size_t)8 * SQ * 2;   // [b][hi][c']
  bf16_t* wveffT  = (bf16_t*)p; p += (size_t)8 * SQ * 2;   // [b][c][hi]
  bf16_t* W2      = (bf16_t*)p; p += (size_t)8 * SQ * 2;   // [b][o][c]
  bf16_t* Hp8     = (bf16_t*)p; p += (size_t)64 * SQ * 2;  // bf16 split-8 partials
  bf16_t* fnT     = (bf16_t*)p; p += ACT * 2;              // [b][n][c]

  // fused front: gram + fnT + weight cvts + Wv transpose
  k_front<<<dim3(2816), 512, 0, stream>>>(f_m, f_n, Wq, Wkv, Wout,
                                          Hp8, fnT, wq_b, wk_b, wout_b, wvT);
  k_reduce8<<<dim3(1024), 256, 0, stream>>>(Hp8, Hb);

  // T1[b][hi][c'] = sum_c Wq[hi][c] H[b][c'][c]
  k_gemm_bt<<<dim3(4, 4, 8), 256, 0, stream>>>(wq_b, Hb, T1, 512, 512, 512,
                                               0, (long long)SQ, (long long)SQ);
  // dots + softmax + wveff fused
  k_dots_wveff<<<dim3(64), 256, 0, stream>>>(T1, wk_b, wvT, wveffT);
  // W2[b][o][c] = sum_hi Wout[o][hi] WvEffT[b][c][hi]
  k_gemm_bt<<<dim3(4, 4, 8), 256, 0, stream>>>(wout_b, wveffT, W2, 512, 512, 512,
                                               0, (long long)SQ, (long long)SQ);
  // y[b][o][n] = sum_c W2[b][o][c] fnT[b][n][c] + bout[o], 256^2 tiles
  k_y256<<<dim3(256), 512, 0, stream>>>(W2, fnT, y, bout);
}

// Round 12
// 115.549 us; speedup vs baseline: 1.3810x; 1.1041x over previous
//
#include <hip/hip_runtime.h>
#include <hip/hip_bf16.h>
#include <stdint.h>

typedef __bf16 bf16_t;
typedef __bf16 bf16x8 __attribute__((ext_vector_type(8)));
typedef float f32x4 __attribute__((ext_vector_type(4)));

#define MFMA_16x16x32(A, B, C) __builtin_amdgcn_mfma_f32_16x16x32_bf16((A), (B), (C), 0, 0, 0)

__device__ inline void gload_lds16(const bf16_t* g, bf16_t* lds) {
  auto* gp = (const __attribute__((address_space(1))) uint32_t*)(uintptr_t)g;
  auto* lp = (__attribute__((address_space(3))) uint32_t*)(uintptr_t)lds;
  __builtin_amdgcn_global_load_lds(gp, lp, 16, 0, 0);
}

// ========== fused front: gram (fabric-bound) || cvt3 + wvT (tiny) ==========
// Roles: [0,256) gram; [256,640) cvt3; [640,768) wvT.  512 threads, 64 KB LDS union.
__global__ __launch_bounds__(512, 2)
void k_front(const float* __restrict__ f_m, const float* __restrict__ f_n,
             const float* __restrict__ Wq, const float* __restrict__ Wkv,
             const float* __restrict__ Wout,
             bf16_t* __restrict__ Hp,
             bf16_t* __restrict__ wq_b, bf16_t* __restrict__ wk_b,
             bf16_t* __restrict__ wout_b, bf16_t* __restrict__ wvT) {
  __shared__ __align__(16) char ldsbuf[65536];
  const int bid = blockIdx.x;
  const int tid = threadIdx.x;

  if (bid < 256) {
    // ---------------- gram role (rounds 8/10/11 verified body) ----------------
    const int xcd = bid & 7, idx = bid >> 3;
    const int mt = idx & 1, nt = (idx >> 1) & 1, ks = idx >> 2;  // ks 0..7
    const int b = xcd;
    const float* Ab = f_n + (size_t)b * 512 * 4096;
    const float* Bb = f_m + (size_t)b * 512 * 4096;
    const int bm = mt * 256, bn = nt * 256;
    const int kbeg = ks * 512;               // 16 steps of BK=32

    const int wave = tid >> 6, lane = tid & 63;
    const int l15 = lane & 15, l4 = lane >> 4;
    const int wm = (wave >> 2) * 128, wn = (wave & 3) * 64;
    const int rsw = (l15 >> 1) & 3;

    bf16_t* As0 = (bf16_t*)ldsbuf;           // [2][8192]
    bf16_t* Bs0 = As0 + 16384;               // [2][8192]

    f32x4 acc[8][4] = {};

    const int rho = tid >> 1, h = tid & 1;
    const int sw = (rho >> 1) & 3;
    const int wo0 = rho * 32 + (((2 * h) ^ sw) * 8);
    const int wo1 = rho * 32 + (((2 * h + 1) ^ sw) * 8);
    const float* ga = Ab + (size_t)(bm + rho) * 4096 + kbeg + h * 16;
    const float* gb = Bb + (size_t)(bn + rho) * 4096 + kbeg + h * 16;

    float4 ra[4], rb[4];
#pragma unroll
    for (int q = 0; q < 4; ++q) {
      ra[q] = *(const float4*)(ga + q * 4);
      rb[q] = *(const float4*)(gb + q * 4);
    }

    int cur = 0;
    for (int i = 0; i < 16; ++i) {
      bf16_t* As = As0 + cur * 8192;
      bf16_t* Bs = Bs0 + cur * 8192;
      bf16_t ta[16], tb[16];
#pragma unroll
      for (int q = 0; q < 4; ++q) {
        ta[q * 4 + 0] = (bf16_t)ra[q].x; ta[q * 4 + 1] = (bf16_t)ra[q].y;
        ta[q * 4 + 2] = (bf16_t)ra[q].z; ta[q * 4 + 3] = (bf16_t)ra[q].w;
        tb[q * 4 + 0] = (bf16_t)rb[q].x; tb[q * 4 + 1] = (bf16_t)rb[q].y;
        tb[q * 4 + 2] = (bf16_t)rb[q].z; tb[q * 4 + 3] = (bf16_t)rb[q].w;
      }
      *(uint4*)(&As[wo0]) = *(uint4*)(ta);
      *(uint4*)(&As[wo1]) = *(uint4*)(ta + 8);
      *(uint4*)(&Bs[wo0]) = *(uint4*)(tb);
      *(uint4*)(&Bs[wo1]) = *(uint4*)(tb + 8);
      if (i + 1 < 16) {
        const float* na = ga + (i + 1) * 32;
        const float* nb = gb + (i + 1) * 32;
#pragma unroll
        for (int q = 0; q < 4; ++q) {
          ra[q] = *(const float4*)(na + q * 4);
          rb[q] = *(const float4*)(nb + q * 4);
        }
      }
      __syncthreads();
      bf16x8 bfr[4];
#pragma unroll
      for (int n = 0; n < 4; ++n)
        bfr[n] = *(const bf16x8*)(&Bs[(wn + n * 16 + l15) * 32 + ((l4 ^ rsw) * 8)]);
#pragma unroll
      for (int m = 0; m < 8; ++m) {
        bf16x8 af = *(const bf16x8*)(&As[(wm + m * 16 + l15) * 32 + ((l4 ^ rsw) * 8)]);
#pragma unroll
        for (int n = 0; n < 4; ++n)
          acc[m][n] = MFMA_16x16x32(af, bfr[n], acc[m][n]);
      }
      cur ^= 1;
    }

    bf16_t* Cb = Hp + (size_t)(b * 8 + ks) * 262144;
#pragma unroll
    for (int m = 0; m < 8; ++m) {
      const int row0 = bm + wm + m * 16 + l4 * 4;
#pragma unroll
      for (int n = 0; n < 4; ++n) {
        const int col = bn + wn + n * 16 + l15;
#pragma unroll
        for (int j = 0; j < 4; ++j)
          Cb[(size_t)(row0 + j) * 512 + col] = (bf16_t)acc[m][n][j];
      }
    }
  } else if (bid < 640) {
    // ---------------- cvt3 role ----------------
    int i = (bid - 256) * 512 + tid;         // 196608 threads, 4 elems each
    int region = i >> 16;
    int e = (i & 65535) * 4;
    const float* src = region == 0 ? Wq : (region == 1 ? Wkv : Wout);
    bf16_t* dst = region == 0 ? wq_b : (region == 1 ? wk_b : wout_b);
    float4 v = *(const float4*)(src + e);
    bf16_t o[4] = {(bf16_t)v.x, (bf16_t)v.y, (bf16_t)v.z, (bf16_t)v.w};
    *(uint2*)(dst + e) = *(uint2*)o;
  } else {
    // ---------------- wvT role: two 32x32 transpose tiles (Wv -> [h][c][64]) ----
    const int half = tid >> 8;
    const int t = tid & 255;
    const int tileIdx = (bid - 640) * 2 + half;   // 0..255
    const int x = tileIdx & 15, yy = (tileIdx >> 4) & 1, z = tileIdx >> 5;
    const int C = 64, N = 512;
    const float* src = Wkv + (size_t)512 * 512 + (size_t)z * C * N;
    bf16_t* dst = wvT + (size_t)z * C * N;
    const int n0 = x * 32, c0 = yy * 32;
    float* tile = (float*)ldsbuf + half * (32 * 33);
    const int tx = t & 31, ty = (t >> 5) & 7;
#pragma unroll
    for (int i = 0; i < 32; i += 8)
      tile[(ty + i) * 33 + tx] = src[(size_t)(c0 + ty + i) * N + (n0 + tx)];
    __syncthreads();
#pragma unroll
    for (int i = 0; i < 32; i += 8)
      dst[(size_t)(n0 + ty + i) * C + (c0 + tx)] = (bf16_t)tile[tx * 33 + ty + i];
  }
}

// ---------- reduce 8 bf16 split-K partials -> bf16 ----------
__global__ __launch_bounds__(256)
void k_reduce8(const bf16_t* __restrict__ p, bf16_t* __restrict__ out) {
  int i = blockIdx.x * blockDim.x + threadIdx.x;  // 262144 threads
  int b = i >> 15;
  int e8 = (i & 32767) * 8;
  const bf16_t* pb = p + (size_t)b * 8 * 262144 + e8;
  float s[8] = {};
#pragma unroll
  for (int ks = 0; ks < 8; ++ks) {
    bf16x8 v = *(const bf16x8*)(pb + (size_t)ks * 262144);
#pragma unroll
    for (int j = 0; j < 8; ++j) s[j] += (float)v[j];
  }
  bf16x8 o;
#pragma unroll
  for (int j = 0; j < 8; ++j) o[j] = (bf16_t)s[j];
  *(bf16x8*)(out + (size_t)b * 262144 + e8) = o;
}

// ---------- small GEMM C[M][N] = A[M][K] B[N][K]^T, 128x128, dbuf (bf16 out) ----------
__global__ __launch_bounds__(256)
void k_gemm_bt(const bf16_t* __restrict__ A, const bf16_t* __restrict__ B,
               bf16_t* __restrict__ Cv, int M, int N, int K,
               long long sA, long long sB, long long sC) {
  const int zb = blockIdx.z;
  A += (size_t)zb * sA;
  B += (size_t)zb * sB;

  const int tid = threadIdx.x;
  const int wave = tid >> 6, lane = tid & 63;
  const int l15 = lane & 15, l4 = lane >> 4;
  const int bm = blockIdx.y * 128, bn = blockIdx.x * 128;
  const int wm = (wave >> 1) * 64, wn = (wave & 1) * 64;

  __shared__ bf16_t As[2][128 * 32];
  __shared__ bf16_t Bs[2][128 * 32];

  f32x4 acc[4][4] = {};

  const int lrow = lane >> 2;
  const int lchunk = (lane & 3) * 8;
  const int ra = wave * 16 + lrow;

  auto stage = [&](int buf, int k0) {
    gload_lds16(&A[(size_t)(bm + ra) * K + k0 + lchunk],      &As[buf][(wave * 16) * 32]);
    gload_lds16(&A[(size_t)(bm + 64 + ra) * K + k0 + lchunk], &As[buf][(64 + wave * 16) * 32]);
    gload_lds16(&B[(size_t)(bn + ra) * K + k0 + lchunk],      &Bs[buf][(wave * 16) * 32]);
    gload_lds16(&B[(size_t)(bn + 64 + ra) * K + k0 + lchunk], &Bs[buf][(64 + wave * 16) * 32]);
  };

  const int nsteps = K / 32;
  stage(0, 0);
  __syncthreads();

  for (int i = 0; i < nsteps; ++i) {
    const int cur = i & 1;
    if (i + 1 < nsteps) stage(cur ^ 1, (i + 1) * 32);
    bf16x8 af[4], bfr[4];
#pragma unroll
    for (int m = 0; m < 4; ++m)
      af[m] = *(const bf16x8*)(&As[cur][(wm + m * 16 + l15) * 32 + l4 * 8]);
#pragma unroll
    for (int n = 0; n < 4; ++n)
      bfr[n] = *(const bf16x8*)(&Bs[cur][(wn + n * 16 + l15) * 32 + l4 * 8]);
#pragma unroll
    for (int m = 0; m < 4; ++m)
#pragma unroll
      for (int n = 0; n < 4; ++n)
        acc[m][n] = MFMA_16x16x32(af[m], bfr[n], acc[m][n]);
    __syncthreads();
  }

#pragma unroll
  for (int m = 0; m < 4; ++m) {
    const int row0 = bm + wm + m * 16 + l4 * 4;
#pragma unroll
    for (int n = 0; n < 4; ++n) {
      const int col = bn + wn + n * 16 + l15;
#pragma unroll
      for (int j = 0; j < 4; ++j)
        (Cv + (size_t)zb * sC)[(size_t)(row0 + j) * N + col] = (bf16_t)acc[m][n][j];
    }
  }
}

// ---------- fused dots + softmax + wveff: one block per (b,h) ----------
__global__ __launch_bounds__(256)
void k_dots_wveff(const bf16_t* __restrict__ T1, const bf16_t* __restrict__ wk,
                  const bf16_t* __restrict__ wvT, bf16_t* __restrict__ wveffT) {
  const int bh = blockIdx.x;
  const int b = bh >> 3, hh = bh & 7;
  const bf16_t* qh = T1 + (size_t)b * 262144 + (size_t)hh * 64 * 512;
  const bf16_t* kh = wk + (size_t)hh * 64 * 512;
  const int tid = threadIdx.x;
  const int wave = tid >> 6, lane = tid & 63;
  const int l15 = lane & 15, l4 = lane >> 4;

  __shared__ float S[64][65];
  __shared__ bf16_t P[64][72];

  {
    const int wm = (wave >> 1) * 32, wn = (wave & 1) * 32;
    f32x4 acc[2][2] = {};
#pragma unroll 2
    for (int k0 = 0; k0 < 512; k0 += 32) {
      bf16x8 af[2], bfr[2];
#pragma unroll
      for (int m = 0; m < 2; ++m)
        af[m] = *(const bf16x8*)(&qh[(size_t)(wm + m * 16 + l15) * 512 + k0 + l4 * 8]);
#pragma unroll
      for (int n = 0; n < 2; ++n)
        bfr[n] = *(const bf16x8*)(&kh[(size_t)(wn + n * 16 + l15) * 512 + k0 + l4 * 8]);
#pragma unroll
      for (int m = 0; m < 2; ++m)
#pragma unroll
        for (int n = 0; n < 2; ++n)
          acc[m][n] = MFMA_16x16x32(af[m], bfr[n], acc[m][n]);
    }
    const float scale = 0.125f;
#pragma unroll
    for (int m = 0; m < 2; ++m)
#pragma unroll
      for (int n = 0; n < 2; ++n)
#pragma unroll
        for (int j = 0; j < 4; ++j)
          S[wm + m * 16 + l4 * 4 + j][wn + n * 16 + l15] = acc[m][n][j] * scale;
  }
  __syncthreads();

  {
    const int r = tid >> 2, seg = (tid & 3) * 16;
    float vals[16];
    float mx = -1e30f;
#pragma unroll
    for (int c = 0; c < 16; ++c) { vals[c] = S[r][seg + c]; mx = fmaxf(mx, vals[c]); }
    mx = fmaxf(mx, __shfl_xor(mx, 1));
    mx = fmaxf(mx, __shfl_xor(mx, 2));
    float sum = 0.f;
#pragma unroll
    for (int c = 0; c < 16; ++c) { vals[c] = __expf(vals[c] - mx); sum += vals[c]; }
    sum += __shfl_xor(sum, 1);
    sum += __shfl_xor(sum, 2);
    const float inv = 1.0f / sum;
    bf16_t pr[16];
#pragma unroll
    for (int c = 0; c < 16; ++c) pr[c] = (bf16_t)(vals[c] * inv);
    *(uint4*)(&P[r][seg]) = *(uint4*)(pr);
    *(uint4*)(&P[r][seg + 8]) = *(uint4*)(pr + 8);
  }
  __syncthreads();

  {
    const bf16_t* av = wvT + (size_t)hh * 512 * 64;
    bf16_t* ob = wveffT + (size_t)b * 262144 + (size_t)hh * 64;
    const int wm = (wave >> 1) * 64, wn = (wave & 1) * 32;
    for (int cm0 = 0; cm0 < 512; cm0 += 128) {
      f32x4 acc[4][2] = {};
#pragma unroll
      for (int ks = 0; ks < 2; ++ks) {
        const int k0 = ks * 32;
        bf16x8 af[4], bfr[2];
#pragma unroll
        for (int m = 0; m < 4; ++m)
          af[m] = *(const bf16x8*)(&av[(size_t)(cm0 + wm + m * 16 + l15) * 64 + k0 + l4 * 8]);
#pragma unroll
        for (int n = 0; n < 2; ++n)
          bfr[n] = *(const bf16x8*)(&P[wn + n * 16 + l15][k0 + l4 * 8]);
#pragma unroll
        for (int m = 0; m < 4; ++m)
#pragma unroll
          for (int n = 0; n < 2; ++n)
            acc[m][n] = MFMA_16x16x32(af[m], bfr[n], acc[m][n]);
      }
#pragma unroll
      for (int m = 0; m < 4; ++m)
#pragma unroll
        for (int n = 0; n < 2; ++n)
#pragma unroll
          for (int j = 0; j < 4; ++j)
            ob[(size_t)(cm0 + wm + m * 16 + l4 * 4 + j) * 512 + wn + n * 16 + l15] =
                (bf16_t)acc[m][n][j];
    }
  }
}

// ---------- y GEMM from f32 B: y[b][o][n] = sum_c W2[b][o][c] * f_n[b][c][n] + bias ----------
// 256x128 tile, 8 waves (4m x 2n).  B staged via in-LDS transpose (F-tile f32 ->
// bf16 Bs with gram's chunk swizzle).  A via gload_lds pre-swizzled (verified path).
__global__ __launch_bounds__(512, 2)
void k_yf32(const bf16_t* __restrict__ A, const float* __restrict__ Bf,
            float* __restrict__ C, const float* __restrict__ bias) {
  const int raw = blockIdx.x;              // 512 blocks
  const int b = raw & 7, c = raw >> 3;     // XCD-affine: xcd = batch
  const int bm = (c & 1) * 256, bn = (c >> 1) * 128;   // M=512, N=4096
  A  += (size_t)b * 262144;
  Bf += (size_t)b * 512 * 4096;
  C  += (size_t)b * 512 * 4096;

  const int tid = threadIdx.x;
  const int wave = tid >> 6, lane = tid & 63;
  const int l15 = lane & 15, l4 = lane >> 4;
  const int wm = (wave >> 1) * 64, wn = (wave & 1) * 64;
  const int rsw = (l15 >> 1) & 3;

  __shared__ bf16_t As[2][256 * 32];   // 32 KB
  __shared__ bf16_t Bs[2][128 * 32];   // 16 KB
  __shared__ float  Ft[32 * 128];      // 16 KB  (total 64 KB exactly)

  f32x4 acc[4][4] = {};

  // A staging (verified y256 path): lane l -> dest row base+(l>>2), phys chunk l&3;
  // source pre-swizzled: logical chunk = (l&3) ^ ((l>>3)&3).
  const int lrow = lane >> 2;
  const int lch = (lane & 3) ^ ((lane >> 3) & 3);
  const bf16_t* srcA = A + (size_t)(bm + wave * 32 + lrow) * 512 + lch * 8;
  bf16_t* dstA = &As[0][wave * 32 * 32];
  const int bufA = 256 * 32;

  // B f32 coalesced load: thread -> F row fr (c), col fc (n)
  const int fr = tid >> 4, fc = (tid & 15) * 8;
  const float* srcB = Bf + (size_t)fr * 4096 + bn + fc;

  // transpose: thread -> Bs row tn (n), c-segment tc; write chunk swizzled by (tn>>1)&3
  const int tn = tid >> 2, tc = (tid & 3) * 8;
  const int wchunk = ((tid & 3) ^ ((tn >> 1) & 3)) * 8;

  float4 rb0 = *(const float4*)(srcB);
  float4 rb1 = *(const float4*)(srcB + 4);
  gload_lds16(srcA, dstA);
  gload_lds16(srcA + 16 * 512, dstA + 512);
  __syncthreads();   // drains prologue A-gload

  int cur = 0;
  for (int i = 0; i < 16; ++i) {
    // phase 1: write F-tile (step i B data; compiler waits on rb loads)
    *(float4*)(&Ft[fr * 128 + fc]) = rb0;
    *(float4*)(&Ft[fr * 128 + fc + 4]) = rb1;
    __syncthreads();   // F ready; A-gload(i) -> As[cur] drained
    // phase 2: transpose F -> Bs[cur] (bf16, swizzled chunks)
    {
      bf16_t tb[8];
#pragma unroll
      for (int q = 0; q < 8; ++q) tb[q] = (bf16_t)Ft[(tc + q) * 128 + tn];
      *(uint4*)(&Bs[cur][tn * 32 + wchunk]) = *(uint4*)tb;
    }
    __syncthreads();   // Bs[cur] ready; F consumed (safe to overwrite next iter)
    // phase 3: prefetch step i+1 (in flight across MFMA below)
    if (i + 1 < 16) {
      const float* nb = srcB + (size_t)(i + 1) * 32 * 4096;
      rb0 = *(const float4*)(nb);
      rb1 = *(const float4*)(nb + 4);
      gload_lds16(srcA + (i + 1) * 32,            dstA + (cur ^ 1) * bufA);
      gload_lds16(srcA + 16 * 512 + (i + 1) * 32, dstA + (cur ^ 1) * bufA + 512);
    }
    // MFMA over As[cur], Bs[cur]
    bf16x8 af[4], bfr[4];
#pragma unroll
    for (int n = 0; n < 4; ++n)
      bfr[n] = *(const bf16x8*)(&Bs[cur][(wn + n * 16 + l15) * 32 + ((l4 ^ rsw) * 8)]);
#pragma unroll
    for (int m = 0; m < 4; ++m)
      af[m] = *(const bf16x8*)(&As[cur][(wm + m * 16 + l15) * 32 + ((l4 ^ rsw) * 8)]);
#pragma unroll
    for (int m = 0; m < 4; ++m)
#pragma unroll
      for (int n = 0; n < 4; ++n)
        acc[m][n] = MFMA_16x16x32(af[m], bfr[n], acc[m][n]);
    cur ^= 1;
  }

#pragma unroll
  for (int m = 0; m < 4; ++m) {
    const int row0 = bm + wm + m * 16 + l4 * 4;
#pragma unroll
    for (int n = 0; n < 4; ++n) {
      const int col = bn + wn + n * 16 + l15;
#pragma unroll
      for (int j = 0; j < 4; ++j)
        C[(size_t)(row0 + j) * 4096 + col] = acc[m][n][j] + bias[row0 + j];
    }
  }
}

extern "C" void kernel_launch(void* const* d_in, const int* in_sizes, int n_in,
                              void* d_out, int out_size, void* d_ws, size_t ws_size,
                              hipStream_t stream) {
  const float* f_m  = (const float*)d_in[0];
  const float* f_n  = (const float*)d_in[1];
  const float* Wq   = (const float*)d_in[2];
  const float* Wkv  = (const float*)d_in[3];
  const float* Wout = (const float*)d_in[4];
  const float* bout = (const float*)d_in[5];
  float* y = (float*)d_out;

  const size_t SQ  = (size_t)512 * 512;
  char* p = (char*)d_ws;
  bf16_t* wq_b    = (bf16_t*)p; p += SQ * 2;
  bf16_t* wk_b    = (bf16_t*)p; p += SQ * 2;
  bf16_t* wout_b  = (bf16_t*)p; p += SQ * 2;
  bf16_t* wvT     = (bf16_t*)p; p += SQ * 2;               // [h][c][64]
  bf16_t* Hb      = (bf16_t*)p; p += (size_t)8 * SQ * 2;   // [b][c'][c]
  bf16_t* T1      = (bf16_t*)p; p += (size_t)8 * SQ * 2;   // [b][hi][c']
  bf16_t* wveffT  = (bf16_t*)p; p += (size_t)8 * SQ * 2;   // [b][c][hi]
  bf16_t* W2      = (bf16_t*)p; p += (size_t)8 * SQ * 2;   // [b][o][c]
  bf16_t* Hp8     = (bf16_t*)p; p += (size_t)64 * SQ * 2;  // bf16 split-8 partials

  // fused front: gram + weight cvts + Wv transpose (no fnT anymore)
  k_front<<<dim3(768), 512, 0, stream>>>(f_m, f_n, Wq, Wkv, Wout,
                                         Hp8, wq_b, wk_b, wout_b, wvT);
  k_reduce8<<<dim3(1024), 256, 0, stream>>>(Hp8, Hb);

  // T1[b][hi][c'] = sum_c Wq[hi][c] H[b][c'][c]
  k_gemm_bt<<<dim3(4, 4, 8), 256, 0, stream>>>(wq_b, Hb, T1, 512, 512, 512,
                                               0, (long long)SQ, (long long)SQ);
  // dots + softmax + wveff fused
  k_dots_wveff<<<dim3(64), 256, 0, stream>>>(T1, wk_b, wvT, wveffT);
  // W2[b][o][c] = sum_hi Wout[o][hi] WvEffT[b][c][hi]
  k_gemm_bt<<<dim3(4, 4, 8), 256, 0, stream>>>(wout_b, wveffT, W2, 512, 512, 512,
                                               0, (long long)SQ, (long long)SQ);
  // y from f32 f_n directly (in-LDS transpose staging), 256x128 tiles
  k_yf32<<<dim3(512), 512, 0, stream>>>(W2, f_n, y, bout);
}

// Round 13
// 113.553 us; speedup vs baseline: 1.4053x; 1.0176x over previous
//
#include <hip/hip_runtime.h>
#include <hip/hip_bf16.h>
#include <stdint.h>

typedef __bf16 bf16_t;
typedef __bf16 bf16x8 __attribute__((ext_vector_type(8)));
typedef float f32x4 __attribute__((ext_vector_type(4)));

#define MFMA_16x16x32(A, B, C) __builtin_amdgcn_mfma_f32_16x16x32_bf16((A), (B), (C), 0, 0, 0)

__device__ inline void gload_lds16(const bf16_t* g, bf16_t* lds) {
  auto* gp = (const __attribute__((address_space(1))) uint32_t*)(uintptr_t)g;
  auto* lp = (__attribute__((address_space(3))) uint32_t*)(uintptr_t)lds;
  __builtin_amdgcn_global_load_lds(gp, lp, 16, 0, 0);
}

// ---------- H partials, 256x256 tile, 8 waves, f32-direct, split-K=8 (round-10 verified) ----------
__global__ __launch_bounds__(512, 2)
void k_gram256(const float* __restrict__ A, const float* __restrict__ B,
               bf16_t* __restrict__ Cp) {
  const int raw = blockIdx.x;              // 256 blocks
  const int xcd = raw & 7, idx = raw >> 3; // XCD-affine: xcd = batch
  const int mt = idx & 1, nt = (idx >> 1) & 1, ks = idx >> 2;  // ks 0..7
  const int b = xcd;
  const float* Ab = A + (size_t)b * 512 * 4096;
  const float* Bb = B + (size_t)b * 512 * 4096;
  const int bm = mt * 256, bn = nt * 256;
  const int kbeg = ks * 512;               // 16 steps of BK=32

  const int tid = threadIdx.x;
  const int wave = tid >> 6, lane = tid & 63;
  const int l15 = lane & 15, l4 = lane >> 4;
  const int wm = (wave >> 2) * 128, wn = (wave & 3) * 64;
  const int rsw = (l15 >> 1) & 3;

  __shared__ bf16_t As[2][256 * 32];
  __shared__ bf16_t Bs[2][256 * 32];

  f32x4 acc[8][4] = {};

  const int rho = tid >> 1, h = tid & 1;
  const int sw = (rho >> 1) & 3;
  const int wo0 = rho * 32 + (((2 * h) ^ sw) * 8);
  const int wo1 = rho * 32 + (((2 * h + 1) ^ sw) * 8);
  const float* ga = Ab + (size_t)(bm + rho) * 4096 + kbeg + h * 16;
  const float* gb = Bb + (size_t)(bn + rho) * 4096 + kbeg + h * 16;

  float4 ra[4], rb[4];
#pragma unroll
  for (int q = 0; q < 4; ++q) {
    ra[q] = *(const float4*)(ga + q * 4);
    rb[q] = *(const float4*)(gb + q * 4);
  }

  int cur = 0;
  for (int i = 0; i < 16; ++i) {
    bf16_t ta[16], tb[16];
#pragma unroll
    for (int q = 0; q < 4; ++q) {
      ta[q * 4 + 0] = (bf16_t)ra[q].x; ta[q * 4 + 1] = (bf16_t)ra[q].y;
      ta[q * 4 + 2] = (bf16_t)ra[q].z; ta[q * 4 + 3] = (bf16_t)ra[q].w;
      tb[q * 4 + 0] = (bf16_t)rb[q].x; tb[q * 4 + 1] = (bf16_t)rb[q].y;
      tb[q * 4 + 2] = (bf16_t)rb[q].z; tb[q * 4 + 3] = (bf16_t)rb[q].w;
    }
    *(uint4*)(&As[cur][wo0]) = *(uint4*)(ta);
    *(uint4*)(&As[cur][wo1]) = *(uint4*)(ta + 8);
    *(uint4*)(&Bs[cur][wo0]) = *(uint4*)(tb);
    *(uint4*)(&Bs[cur][wo1]) = *(uint4*)(tb + 8);
    if (i + 1 < 16) {
      const float* na = ga + (i + 1) * 32;
      const float* nb = gb + (i + 1) * 32;
#pragma unroll
      for (int q = 0; q < 4; ++q) {
        ra[q] = *(const float4*)(na + q * 4);
        rb[q] = *(const float4*)(nb + q * 4);
      }
    }
    __syncthreads();
    bf16x8 bfr[4];
#pragma unroll
    for (int n = 0; n < 4; ++n)
      bfr[n] = *(const bf16x8*)(&Bs[cur][(wn + n * 16 + l15) * 32 + ((l4 ^ rsw) * 8)]);
#pragma unroll
    for (int m = 0; m < 8; ++m) {
      bf16x8 af = *(const bf16x8*)(&As[cur][(wm + m * 16 + l15) * 32 + ((l4 ^ rsw) * 8)]);
#pragma unroll
      for (int n = 0; n < 4; ++n)
        acc[m][n] = MFMA_16x16x32(af, bfr[n], acc[m][n]);
    }
    cur ^= 1;
  }

  bf16_t* Cb = Cp + (size_t)(b * 8 + ks) * 262144;
#pragma unroll
  for (int m = 0; m < 8; ++m) {
    const int row0 = bm + wm + m * 16 + l4 * 4;
#pragma unroll
    for (int n = 0; n < 4; ++n) {
      const int col = bn + wn + n * 16 + l15;
#pragma unroll
      for (int j = 0; j < 4; ++j)
        Cb[(size_t)(row0 + j) * 512 + col] = (bf16_t)acc[m][n][j];
    }
  }
}

// ---------- reduce8 + weight-prep roles (256-thread blocks) ----------
// [0,1024): reduce 8 bf16 partials -> Hb.  [1024,1792): cvt3.  [1792,2048): wvT.
__global__ __launch_bounds__(256)
void k_reduce_prep(const bf16_t* __restrict__ p, bf16_t* __restrict__ out,
                   const float* __restrict__ Wq, const float* __restrict__ Wkv,
                   const float* __restrict__ Wout,
                   bf16_t* __restrict__ wq_b, bf16_t* __restrict__ wk_b,
                   bf16_t* __restrict__ wout_b, bf16_t* __restrict__ wvT) {
  __shared__ float tile[32][33];
  const int bid = blockIdx.x;
  const int tid = threadIdx.x;

  if (bid < 1024) {
    // ---- reduce8 (round-10 verified body) ----
    int i = bid * 256 + tid;
    int b = i >> 15;
    int e8 = (i & 32767) * 8;
    const bf16_t* pb = p + (size_t)b * 8 * 262144 + e8;
    float s[8] = {};
#pragma unroll
    for (int ks = 0; ks < 8; ++ks) {
      bf16x8 v = *(const bf16x8*)(pb + (size_t)ks * 262144);
#pragma unroll
      for (int j = 0; j < 8; ++j) s[j] += (float)v[j];
    }
    bf16x8 o;
#pragma unroll
    for (int j = 0; j < 8; ++j) o[j] = (bf16_t)s[j];
    *(bf16x8*)(out + (size_t)b * 262144 + e8) = o;
  } else if (bid < 1792) {
    // ---- cvt3: 4 f32->bf16 per thread across 3 weight mats ----
    int i = (bid - 1024) * 256 + tid;        // 196608 threads
    int region = i >> 16;
    int e = (i & 65535) * 4;
    const float* src = region == 0 ? Wq : (region == 1 ? Wkv : Wout);
    bf16_t* dst = region == 0 ? wq_b : (region == 1 ? wk_b : wout_b);
    float4 v = *(const float4*)(src + e);
    bf16_t o[4] = {(bf16_t)v.x, (bf16_t)v.y, (bf16_t)v.z, (bf16_t)v.w};
    *(uint2*)(dst + e) = *(uint2*)o;
  } else {
    // ---- wvT: one 32x32 transpose tile (Wv -> [h][c][64]) per block ----
    const int rel = bid - 1792;              // 0..255
    const int x = rel & 15, yy = (rel >> 4) & 1, z = rel >> 5;
    const int C = 64, N = 512;
    const float* src = Wkv + (size_t)512 * 512 + (size_t)z * C * N;
    bf16_t* dst = wvT + (size_t)z * C * N;
    const int n0 = x * 32, c0 = yy * 32;
    const int tx = tid & 31, ty = tid >> 5;  // 32 x 8
#pragma unroll
    for (int i = 0; i < 32; i += 8)
      tile[ty + i][tx] = src[(size_t)(c0 + ty + i) * N + (n0 + tx)];
    __syncthreads();
#pragma unroll
    for (int i = 0; i < 32; i += 8)
      dst[(size_t)(n0 + ty + i) * C + (c0 + tx)] = (bf16_t)tile[tx][ty + i];
  }
}

// ---------- small GEMM C[M][N] = A[M][K] B[N][K]^T, 128x128, dbuf (bf16 out) ----------
__global__ __launch_bounds__(256)
void k_gemm_bt(const bf16_t* __restrict__ A, const bf16_t* __restrict__ B,
               bf16_t* __restrict__ Cv, int M, int N, int K,
               long long sA, long long sB, long long sC) {
  const int zb = blockIdx.z;
  A += (size_t)zb * sA;
  B += (size_t)zb * sB;

  const int tid = threadIdx.x;
  const int wave = tid >> 6, lane = tid & 63;
  const int l15 = lane & 15, l4 = lane >> 4;
  const int bm = blockIdx.y * 128, bn = blockIdx.x * 128;
  const int wm = (wave >> 1) * 64, wn = (wave & 1) * 64;

  __shared__ bf16_t As[2][128 * 32];
  __shared__ bf16_t Bs[2][128 * 32];

  f32x4 acc[4][4] = {};

  const int lrow = lane >> 2;
  const int lchunk = (lane & 3) * 8;
  const int ra = wave * 16 + lrow;

  auto stage = [&](int buf, int k0) {
    gload_lds16(&A[(size_t)(bm + ra) * K + k0 + lchunk],      &As[buf][(wave * 16) * 32]);
    gload_lds16(&A[(size_t)(bm + 64 + ra) * K + k0 + lchunk], &As[buf][(64 + wave * 16) * 32]);
    gload_lds16(&B[(size_t)(bn + ra) * K + k0 + lchunk],      &Bs[buf][(wave * 16) * 32]);
    gload_lds16(&B[(size_t)(bn + 64 + ra) * K + k0 + lchunk], &Bs[buf][(64 + wave * 16) * 32]);
  };

  const int nsteps = K / 32;
  stage(0, 0);
  __syncthreads();

  for (int i = 0; i < nsteps; ++i) {
    const int cur = i & 1;
    if (i + 1 < nsteps) stage(cur ^ 1, (i + 1) * 32);
    bf16x8 af[4], bfr[4];
#pragma unroll
    for (int m = 0; m < 4; ++m)
      af[m] = *(const bf16x8*)(&As[cur][(wm + m * 16 + l15) * 32 + l4 * 8]);
#pragma unroll
    for (int n = 0; n < 4; ++n)
      bfr[n] = *(const bf16x8*)(&Bs[cur][(wn + n * 16 + l15) * 32 + l4 * 8]);
#pragma unroll
    for (int m = 0; m < 4; ++m)
#pragma unroll
      for (int n = 0; n < 4; ++n)
        acc[m][n] = MFMA_16x16x32(af[m], bfr[n], acc[m][n]);
    __syncthreads();
  }

#pragma unroll
  for (int m = 0; m < 4; ++m) {
    const int row0 = bm + wm + m * 16 + l4 * 4;
#pragma unroll
    for (int n = 0; n < 4; ++n) {
      const int col = bn + wn + n * 16 + l15;
#pragma unroll
      for (int j = 0; j < 4; ++j)
        (Cv + (size_t)zb * sC)[(size_t)(row0 + j) * N + col] = (bf16_t)acc[m][n][j];
    }
  }
}

// ---------- fused dots + softmax + wveff: one block per (b,h) ----------
__global__ __launch_bounds__(256)
void k_dots_wveff(const bf16_t* __restrict__ T1, const bf16_t* __restrict__ wk,
                  const bf16_t* __restrict__ wvT, bf16_t* __restrict__ wveffT) {
  const int bh = blockIdx.x;
  const int b = bh >> 3, hh = bh & 7;
  const bf16_t* qh = T1 + (size_t)b * 262144 + (size_t)hh * 64 * 512;
  const bf16_t* kh = wk + (size_t)hh * 64 * 512;
  const int tid = threadIdx.x;
  const int wave = tid >> 6, lane = tid & 63;
  const int l15 = lane & 15, l4 = lane >> 4;

  __shared__ float S[64][65];
  __shared__ bf16_t P[64][72];

  {
    const int wm = (wave >> 1) * 32, wn = (wave & 1) * 32;
    f32x4 acc[2][2] = {};
#pragma unroll 2
    for (int k0 = 0; k0 < 512; k0 += 32) {
      bf16x8 af[2], bfr[2];
#pragma unroll
      for (int m = 0; m < 2; ++m)
        af[m] = *(const bf16x8*)(&qh[(size_t)(wm + m * 16 + l15) * 512 + k0 + l4 * 8]);
#pragma unroll
      for (int n = 0; n < 2; ++n)
        bfr[n] = *(const bf16x8*)(&kh[(size_t)(wn + n * 16 + l15) * 512 + k0 + l4 * 8]);
#pragma unroll
      for (int m = 0; m < 2; ++m)
#pragma unroll
        for (int n = 0; n < 2; ++n)
          acc[m][n] = MFMA_16x16x32(af[m], bfr[n], acc[m][n]);
    }
    const float scale = 0.125f;
#pragma unroll
    for (int m = 0; m < 2; ++m)
#pragma unroll
      for (int n = 0; n < 2; ++n)
#pragma unroll
        for (int j = 0; j < 4; ++j)
          S[wm + m * 16 + l4 * 4 + j][wn + n * 16 + l15] = acc[m][n][j] * scale;
  }
  __syncthreads();

  {
    const int r = tid >> 2, seg = (tid & 3) * 16;
    float vals[16];
    float mx = -1e30f;
#pragma unroll
    for (int c = 0; c < 16; ++c) { vals[c] = S[r][seg + c]; mx = fmaxf(mx, vals[c]); }
    mx = fmaxf(mx, __shfl_xor(mx, 1));
    mx = fmaxf(mx, __shfl_xor(mx, 2));
    float sum = 0.f;
#pragma unroll
    for (int c = 0; c < 16; ++c) { vals[c] = __expf(vals[c] - mx); sum += vals[c]; }
    sum += __shfl_xor(sum, 1);
    sum += __shfl_xor(sum, 2);
    const float inv = 1.0f / sum;
    bf16_t pr[16];
#pragma unroll
    for (int c = 0; c < 16; ++c) pr[c] = (bf16_t)(vals[c] * inv);
    *(uint4*)(&P[r][seg]) = *(uint4*)(pr);
    *(uint4*)(&P[r][seg + 8]) = *(uint4*)(pr + 8);
  }
  __syncthreads();

  {
    const bf16_t* av = wvT + (size_t)hh * 512 * 64;
    bf16_t* ob = wveffT + (size_t)b * 262144 + (size_t)hh * 64;
    const int wm = (wave >> 1) * 64, wn = (wave & 1) * 32;
    for (int cm0 = 0; cm0 < 512; cm0 += 128) {
      f32x4 acc[4][2] = {};
#pragma unroll
      for (int ks = 0; ks < 2; ++ks) {
        const int k0 = ks * 32;
        bf16x8 af[4], bfr[2];
#pragma unroll
        for (int m = 0; m < 4; ++m)
          af[m] = *(const bf16x8*)(&av[(size_t)(cm0 + wm + m * 16 + l15) * 64 + k0 + l4 * 8]);
#pragma unroll
        for (int n = 0; n < 2; ++n)
          bfr[n] = *(const bf16x8*)(&P[wn + n * 16 + l15][k0 + l4 * 8]);
#pragma unroll
        for (int m = 0; m < 4; ++m)
#pragma unroll
          for (int n = 0; n < 2; ++n)
            acc[m][n] = MFMA_16x16x32(af[m], bfr[n], acc[m][n]);
      }
#pragma unroll
      for (int m = 0; m < 4; ++m)
#pragma unroll
        for (int n = 0; n < 2; ++n)
#pragma unroll
          for (int j = 0; j < 4; ++j)
            ob[(size_t)(cm0 + wm + m * 16 + l4 * 4 + j) * 512 + wn + n * 16 + l15] =
                (bf16_t)acc[m][n][j];
    }
  }
}

// ---------- y GEMM from f32 B (round-12 verified): 256x128, in-LDS transpose staging ----------
__global__ __launch_bounds__(512, 2)
void k_yf32(const bf16_t* __restrict__ A, const float* __restrict__ Bf,
            float* __restrict__ C, const float* __restrict__ bias) {
  const int raw = blockIdx.x;              // 512 blocks
  const int b = raw & 7, c = raw >> 3;     // XCD-affine: xcd = batch
  const int bm = (c & 1) * 256, bn = (c >> 1) * 128;   // M=512, N=4096
  A  += (size_t)b * 262144;
  Bf += (size_t)b * 512 * 4096;
  C  += (size_t)b * 512 * 4096;

  const int tid = threadIdx.x;
  const int wave = tid >> 6, lane = tid & 63;
  const int l15 = lane & 15, l4 = lane >> 4;
  const int wm = (wave >> 1) * 64, wn = (wave & 1) * 64;
  const int rsw = (l15 >> 1) & 3;

  __shared__ bf16_t As[2][256 * 32];   // 32 KB
  __shared__ bf16_t Bs[2][128 * 32];   // 16 KB
  __shared__ float  Ft[32 * 128];      // 16 KB

  f32x4 acc[4][4] = {};

  const int lrow = lane >> 2;
  const int lch = (lane & 3) ^ ((lane >> 3) & 3);
  const bf16_t* srcA = A + (size_t)(bm + wave * 32 + lrow) * 512 + lch * 8;
  bf16_t* dstA = &As[0][wave * 32 * 32];
  const int bufA = 256 * 32;

  const int fr = tid >> 4, fc = (tid & 15) * 8;
  const float* srcB = Bf + (size_t)fr * 4096 + bn + fc;

  const int tn = tid >> 2, tc = (tid & 3) * 8;
  const int wchunk = ((tid & 3) ^ ((tn >> 1) & 3)) * 8;

  float4 rb0 = *(const float4*)(srcB);
  float4 rb1 = *(const float4*)(srcB + 4);
  gload_lds16(srcA, dstA);
  gload_lds16(srcA + 16 * 512, dstA + 512);
  __syncthreads();

  int cur = 0;
  for (int i = 0; i < 16; ++i) {
    *(float4*)(&Ft[fr * 128 + fc]) = rb0;
    *(float4*)(&Ft[fr * 128 + fc + 4]) = rb1;
    __syncthreads();
    {
      bf16_t tb[8];
#pragma unroll
      for (int q = 0; q < 8; ++q) tb[q] = (bf16_t)Ft[(tc + q) * 128 + tn];
      *(uint4*)(&Bs[cur][tn * 32 + wchunk]) = *(uint4*)tb;
    }
    __syncthreads();
    if (i + 1 < 16) {
      const float* nb = srcB + (size_t)(i + 1) * 32 * 4096;
      rb0 = *(const float4*)(nb);
      rb1 = *(const float4*)(nb + 4);
      gload_lds16(srcA + (i + 1) * 32,            dstA + (cur ^ 1) * bufA);
      gload_lds16(srcA + 16 * 512 + (i + 1) * 32, dstA + (cur ^ 1) * bufA + 512);
    }
    bf16x8 af[4], bfr[4];
#pragma unroll
    for (int n = 0; n < 4; ++n)
      bfr[n] = *(const bf16x8*)(&Bs[cur][(wn + n * 16 + l15) * 32 + ((l4 ^ rsw) * 8)]);
#pragma unroll
    for (int m = 0; m < 4; ++m)
      af[m] = *(const bf16x8*)(&As[cur][(wm + m * 16 + l15) * 32 + ((l4 ^ rsw) * 8)]);
#pragma unroll
    for (int m = 0; m < 4; ++m)
#pragma unroll
      for (int n = 0; n < 4; ++n)
        acc[m][n] = MFMA_16x16x32(af[m], bfr[n], acc[m][n]);
    cur ^= 1;
  }

#pragma unroll
  for (int m = 0; m < 4; ++m) {
    const int row0 = bm + wm + m * 16 + l4 * 4;
#pragma unroll
    for (int n = 0; n < 4; ++n) {
      const int col = bn + wn + n * 16 + l15;
#pragma unroll
      for (int j = 0; j < 4; ++j)
        C[(size_t)(row0 + j) * 4096 + col] = acc[m][n][j] + bias[row0 + j];
    }
  }
}

extern "C" void kernel_launch(void* const* d_in, const int* in_sizes, int n_in,
                              void* d_out, int out_size, void* d_ws, size_t ws_size,
                              hipStream_t stream) {
  const float* f_m  = (const float*)d_in[0];
  const float* f_n  = (const float*)d_in[1];
  const float* Wq   = (const float*)d_in[2];
  const float* Wkv  = (const float*)d_in[3];
  const float* Wout = (const float*)d_in[4];
  const float* bout = (const float*)d_in[5];
  float* y = (float*)d_out;

  const size_t SQ  = (size_t)512 * 512;
  char* p = (char*)d_ws;
  bf16_t* wq_b    = (bf16_t*)p; p += SQ * 2;
  bf16_t* wk_b    = (bf16_t*)p; p += SQ * 2;
  bf16_t* wout_b  = (bf16_t*)p; p += SQ * 2;
  bf16_t* wvT     = (bf16_t*)p; p += SQ * 2;               // [h][c][64]
  bf16_t* Hb      = (bf16_t*)p; p += (size_t)8 * SQ * 2;   // [b][c'][c]
  bf16_t* T1      = (bf16_t*)p; p += (size_t)8 * SQ * 2;   // [b][hi][c']
  bf16_t* wveffT  = (bf16_t*)p; p += (size_t)8 * SQ * 2;   // [b][c][hi]
  bf16_t* W2      = (bf16_t*)p; p += (size_t)8 * SQ * 2;   // [b][o][c]
  bf16_t* Hp8     = (bf16_t*)p; p += (size_t)64 * SQ * 2;  // bf16 split-8 partials

  // gram standalone (un-fused: round-10 config measured 47-49 us)
  k_gram256<<<dim3(256), 512, 0, stream>>>(f_n, f_m, Hp8);
  // reduce8 + weight cvt + Wv transpose in one grid
  k_reduce_prep<<<dim3(2048), 256, 0, stream>>>(Hp8, Hb, Wq, Wkv, Wout,
                                                wq_b, wk_b, wout_b, wvT);

  // T1[b][hi][c'] = sum_c Wq[hi][c] H[b][c'][c]
  k_gemm_bt<<<dim3(4, 4, 8), 256, 0, stream>>>(wq_b, Hb, T1, 512, 512, 512,
                                               0, (long long)SQ, (long long)SQ);
  // dots + softmax + wveff fused
  k_dots_wveff<<<dim3(64), 256, 0, stream>>>(T1, wk_b, wvT, wveffT);
  // W2[b][o][c] = sum_hi Wout[o][hi] WvEffT[b][c][hi]
  k_gemm_bt<<<dim3(4, 4, 8), 256, 0, stream>>>(wout_b, wveffT, W2, 512, 512, 512,
                                               0, (long long)SQ, (long long)SQ);
  // y from f32 f_n directly (in-LDS transpose staging), 256x128 tiles
  k_yf32<<<dim3(512), 512, 0, stream>>>(W2, f_n, y, bout);
}

// Round 14
// 110.565 us; speedup vs baseline: 1.4433x; 1.0270x over previous
//
#include <hip/hip_runtime.h>
#include <hip/hip_bf16.h>
#include <stdint.h>

typedef __bf16 bf16_t;
typedef __bf16 bf16x8 __attribute__((ext_vector_type(8)));
typedef float f32x4 __attribute__((ext_vector_type(4)));

#define MFMA_16x16x32(A, B, C) __builtin_amdgcn_mfma_f32_16x16x32_bf16((A), (B), (C), 0, 0, 0)

__device__ inline void gload_lds16(const bf16_t* g, bf16_t* lds) {
  auto* gp = (const __attribute__((address_space(1))) uint32_t*)(uintptr_t)g;
  auto* lp = (__attribute__((address_space(3))) uint32_t*)(uintptr_t)lds;
  __builtin_amdgcn_global_load_lds(gp, lp, 16, 0, 0);
}

// ---------- H partials, 256x256 tile, 8 waves, f32-direct, split-K=8 ----------
// Round-13 body with 2-DEEP register prefetch (loads for step i+2 issued at step i;
// two named reg sets, 2-step unrolled loop -> all indexing static).
__global__ __launch_bounds__(512, 2)
void k_gram256(const float* __restrict__ A, const float* __restrict__ B,
               bf16_t* __restrict__ Cp) {
  const int raw = blockIdx.x;              // 256 blocks
  const int xcd = raw & 7, idx = raw >> 3; // XCD-affine: xcd = batch
  const int mt = idx & 1, nt = (idx >> 1) & 1, ks = idx >> 2;  // ks 0..7
  const int b = xcd;
  const float* Ab = A + (size_t)b * 512 * 4096;
  const float* Bb = B + (size_t)b * 512 * 4096;
  const int bm = mt * 256, bn = nt * 256;
  const int kbeg = ks * 512;               // 16 steps of BK=32

  const int tid = threadIdx.x;
  const int wave = tid >> 6, lane = tid & 63;
  const int l15 = lane & 15, l4 = lane >> 4;
  const int wm = (wave >> 2) * 128, wn = (wave & 3) * 64;
  const int rsw = (l15 >> 1) & 3;

  __shared__ bf16_t As[2][256 * 32];
  __shared__ bf16_t Bs[2][256 * 32];

  f32x4 acc[8][4] = {};

  const int rho = tid >> 1, h = tid & 1;
  const int sw = (rho >> 1) & 3;
  const int wo0 = rho * 32 + (((2 * h) ^ sw) * 8);
  const int wo1 = rho * 32 + (((2 * h + 1) ^ sw) * 8);
  const float* ga = Ab + (size_t)(bm + rho) * 4096 + kbeg + h * 16;
  const float* gb = Bb + (size_t)(bn + rho) * 4096 + kbeg + h * 16;

  // two register prefetch sets (static names -> no scratch, rule #20)
  float4 raA[4], rbA[4], raB[4], rbB[4];
#pragma unroll
  for (int q = 0; q < 4; ++q) {            // step 0 -> set A
    raA[q] = *(const float4*)(ga + q * 4);
    rbA[q] = *(const float4*)(gb + q * 4);
  }
#pragma unroll
  for (int q = 0; q < 4; ++q) {            // step 1 -> set B
    raB[q] = *(const float4*)(ga + 32 + q * 4);
    rbB[q] = *(const float4*)(gb + 32 + q * 4);
  }

#pragma unroll 1
  for (int i = 0; i < 16; i += 2) {
    // ======== step i (even): buffer 0, register set A ========
    {
      bf16_t ta[16], tb[16];
#pragma unroll
      for (int q = 0; q < 4; ++q) {
        ta[q * 4 + 0] = (bf16_t)raA[q].x; ta[q * 4 + 1] = (bf16_t)raA[q].y;
        ta[q * 4 + 2] = (bf16_t)raA[q].z; ta[q * 4 + 3] = (bf16_t)raA[q].w;
        tb[q * 4 + 0] = (bf16_t)rbA[q].x; tb[q * 4 + 1] = (bf16_t)rbA[q].y;
        tb[q * 4 + 2] = (bf16_t)rbA[q].z; tb[q * 4 + 3] = (bf16_t)rbA[q].w;
      }
      *(uint4*)(&As[0][wo0]) = *(uint4*)(ta);
      *(uint4*)(&As[0][wo1]) = *(uint4*)(ta + 8);
      *(uint4*)(&Bs[0][wo0]) = *(uint4*)(tb);
      *(uint4*)(&Bs[0][wo1]) = *(uint4*)(tb + 8);
      if (i + 2 < 16) {                    // prefetch step i+2 -> set A
        const float* na = ga + (i + 2) * 32;
        const float* nb = gb + (i + 2) * 32;
#pragma unroll
        for (int q = 0; q < 4; ++q) {
          raA[q] = *(const float4*)(na + q * 4);
          rbA[q] = *(const float4*)(nb + q * 4);
        }
      }
      __syncthreads();
      bf16x8 bfr[4];
#pragma unroll
      for (int n = 0; n < 4; ++n)
        bfr[n] = *(const bf16x8*)(&Bs[0][(wn + n * 16 + l15) * 32 + ((l4 ^ rsw) * 8)]);
#pragma unroll
      for (int m = 0; m < 8; ++m) {
        bf16x8 af = *(const bf16x8*)(&As[0][(wm + m * 16 + l15) * 32 + ((l4 ^ rsw) * 8)]);
#pragma unroll
        for (int n = 0; n < 4; ++n)
          acc[m][n] = MFMA_16x16x32(af, bfr[n], acc[m][n]);
      }
    }
    // ======== step i+1 (odd): buffer 1, register set B ========
    {
      bf16_t ta[16], tb[16];
#pragma unroll
      for (int q = 0; q < 4; ++q) {
        ta[q * 4 + 0] = (bf16_t)raB[q].x; ta[q * 4 + 1] = (bf16_t)raB[q].y;
        ta[q * 4 + 2] = (bf16_t)raB[q].z; ta[q * 4 + 3] = (bf16_t)raB[q].w;
        tb[q * 4 + 0] = (bf16_t)rbB[q].x; tb[q * 4 + 1] = (bf16_t)rbB[q].y;
        tb[q * 4 + 2] = (bf16_t)rbB[q].z; tb[q * 4 + 3] = (bf16_t)rbB[q].w;
      }
      *(uint4*)(&As[1][wo0]) = *(uint4*)(ta);
      *(uint4*)(&As[1][wo1]) = *(uint4*)(ta + 8);
      *(uint4*)(&Bs[1][wo0]) = *(uint4*)(tb);
      *(uint4*)(&Bs[1][wo1]) = *(uint4*)(tb + 8);
      if (i + 3 < 16) {                    // prefetch step i+3 -> set B
        const float* na = ga + (i + 3) * 32;
        const float* nb = gb + (i + 3) * 32;
#pragma unroll
        for (int q = 0; q < 4; ++q) {
          raB[q] = *(const float4*)(na + q * 4);
          rbB[q] = *(const float4*)(nb + q * 4);
        }
      }
      __syncthreads();
      bf16x8 bfr[4];
#pragma unroll
      for (int n = 0; n < 4; ++n)
        bfr[n] = *(const bf16x8*)(&Bs[1][(wn + n * 16 + l15) * 32 + ((l4 ^ rsw) * 8)]);
#pragma unroll
      for (int m = 0; m < 8; ++m) {
        bf16x8 af = *(const bf16x8*)(&As[1][(wm + m * 16 + l15) * 32 + ((l4 ^ rsw) * 8)]);
#pragma unroll
        for (int n = 0; n < 4; ++n)
          acc[m][n] = MFMA_16x16x32(af, bfr[n], acc[m][n]);
      }
    }
  }

  bf16_t* Cb = Cp + (size_t)(b * 8 + ks) * 262144;
#pragma unroll
  for (int m = 0; m < 8; ++m) {
    const int row0 = bm + wm + m * 16 + l4 * 4;
#pragma unroll
    for (int n = 0; n < 4; ++n) {
      const int col = bn + wn + n * 16 + l15;
#pragma unroll
      for (int j = 0; j < 4; ++j)
        Cb[(size_t)(row0 + j) * 512 + col] = (bf16_t)acc[m][n][j];
    }
  }
}

// ---------- reduce8 + weight-prep roles (256-thread blocks) ----------
// [0,1024): reduce 8 bf16 partials -> Hb.  [1024,1792): cvt3.  [1792,2048): wvT.
__global__ __launch_bounds__(256)
void k_reduce_prep(const bf16_t* __restrict__ p, bf16_t* __restrict__ out,
                   const float* __restrict__ Wq, const float* __restrict__ Wkv,
                   const float* __restrict__ Wout,
                   bf16_t* __restrict__ wq_b, bf16_t* __restrict__ wk_b,
                   bf16_t* __restrict__ wout_b, bf16_t* __restrict__ wvT) {
  __shared__ float tile[32][33];
  const int bid = blockIdx.x;
  const int tid = threadIdx.x;

  if (bid < 1024) {
    int i = bid * 256 + tid;
    int b = i >> 15;
    int e8 = (i & 32767) * 8;
    const bf16_t* pb = p + (size_t)b * 8 * 262144 + e8;
    float s[8] = {};
#pragma unroll
    for (int ks = 0; ks < 8; ++ks) {
      bf16x8 v = *(const bf16x8*)(pb + (size_t)ks * 262144);
#pragma unroll
      for (int j = 0; j < 8; ++j) s[j] += (float)v[j];
    }
    bf16x8 o;
#pragma unroll
    for (int j = 0; j < 8; ++j) o[j] = (bf16_t)s[j];
    *(bf16x8*)(out + (size_t)b * 262144 + e8) = o;
  } else if (bid < 1792) {
    int i = (bid - 1024) * 256 + tid;
    int region = i >> 16;
    int e = (i & 65535) * 4;
    const float* src = region == 0 ? Wq : (region == 1 ? Wkv : Wout);
    bf16_t* dst = region == 0 ? wq_b : (region == 1 ? wk_b : wout_b);
    float4 v = *(const float4*)(src + e);
    bf16_t o[4] = {(bf16_t)v.x, (bf16_t)v.y, (bf16_t)v.z, (bf16_t)v.w};
    *(uint2*)(dst + e) = *(uint2*)o;
  } else {
    const int rel = bid - 1792;
    const int x = rel & 15, yy = (rel >> 4) & 1, z = rel >> 5;
    const int C = 64, N = 512;
    const float* src = Wkv + (size_t)512 * 512 + (size_t)z * C * N;
    bf16_t* dst = wvT + (size_t)z * C * N;
    const int n0 = x * 32, c0 = yy * 32;
    const int tx = tid & 31, ty = tid >> 5;
#pragma unroll
    for (int i = 0; i < 32; i += 8)
      tile[ty + i][tx] = src[(size_t)(c0 + ty + i) * N + (n0 + tx)];
    __syncthreads();
#pragma unroll
    for (int i = 0; i < 32; i += 8)
      dst[(size_t)(n0 + ty + i) * C + (c0 + tx)] = (bf16_t)tile[tx][ty + i];
  }
}

// ---------- small GEMM C[M][N] = A[M][K] B[N][K]^T, 128x128, dbuf (bf16 out) ----------
__global__ __launch_bounds__(256)
void k_gemm_bt(const bf16_t* __restrict__ A, const bf16_t* __restrict__ B,
               bf16_t* __restrict__ Cv, int M, int N, int K,
               long long sA, long long sB, long long sC) {
  const int zb = blockIdx.z;
  A += (size_t)zb * sA;
  B += (size_t)zb * sB;

  const int tid = threadIdx.x;
  const int wave = tid >> 6, lane = tid & 63;
  const int l15 = lane & 15, l4 = lane >> 4;
  const int bm = blockIdx.y * 128, bn = blockIdx.x * 128;
  const int wm = (wave >> 1) * 64, wn = (wave & 1) * 64;

  __shared__ bf16_t As[2][128 * 32];
  __shared__ bf16_t Bs[2][128 * 32];

  f32x4 acc[4][4] = {};

  const int lrow = lane >> 2;
  const int lchunk = (lane & 3) * 8;
  const int ra = wave * 16 + lrow;

  auto stage = [&](int buf, int k0) {
    gload_lds16(&A[(size_t)(bm + ra) * K + k0 + lchunk],      &As[buf][(wave * 16) * 32]);
    gload_lds16(&A[(size_t)(bm + 64 + ra) * K + k0 + lchunk], &As[buf][(64 + wave * 16) * 32]);
    gload_lds16(&B[(size_t)(bn + ra) * K + k0 + lchunk],      &Bs[buf][(wave * 16) * 32]);
    gload_lds16(&B[(size_t)(bn + 64 + ra) * K + k0 + lchunk], &Bs[buf][(64 + wave * 16) * 32]);
  };

  const int nsteps = K / 32;
  stage(0, 0);
  __syncthreads();

  for (int i = 0; i < nsteps; ++i) {
    const int cur = i & 1;
    if (i + 1 < nsteps) stage(cur ^ 1, (i + 1) * 32);
    bf16x8 af[4], bfr[4];
#pragma unroll
    for (int m = 0; m < 4; ++m)
      af[m] = *(const bf16x8*)(&As[cur][(wm + m * 16 + l15) * 32 + l4 * 8]);
#pragma unroll
    for (int n = 0; n < 4; ++n)
      bfr[n] = *(const bf16x8*)(&Bs[cur][(wn + n * 16 + l15) * 32 + l4 * 8]);
#pragma unroll
    for (int m = 0; m < 4; ++m)
#pragma unroll
      for (int n = 0; n < 4; ++n)
        acc[m][n] = MFMA_16x16x32(af[m], bfr[n], acc[m][n]);
    __syncthreads();
  }

#pragma unroll
  for (int m = 0; m < 4; ++m) {
    const int row0 = bm + wm + m * 16 + l4 * 4;
#pragma unroll
    for (int n = 0; n < 4; ++n) {
      const int col = bn + wn + n * 16 + l15;
#pragma unroll
      for (int j = 0; j < 4; ++j)
        (Cv + (size_t)zb * sC)[(size_t)(row0 + j) * N + col] = (bf16_t)acc[m][n][j];
    }
  }
}

// ---------- fused dots + softmax + wveff: one block per (b,h) ----------
__global__ __launch_bounds__(256)
void k_dots_wveff(const bf16_t* __restrict__ T1, const bf16_t* __restrict__ wk,
                  const bf16_t* __restrict__ wvT, bf16_t* __restrict__ wveffT) {
  const int bh = blockIdx.x;
  const int b = bh >> 3, hh = bh & 7;
  const bf16_t* qh = T1 + (size_t)b * 262144 + (size_t)hh * 64 * 512;
  const bf16_t* kh = wk + (size_t)hh * 64 * 512;
  const int tid = threadIdx.x;
  const int wave = tid >> 6, lane = tid & 63;
  const int l15 = lane & 15, l4 = lane >> 4;

  __shared__ float S[64][65];
  __shared__ bf16_t P[64][72];

  {
    const int wm = (wave >> 1) * 32, wn = (wave & 1) * 32;
    f32x4 acc[2][2] = {};
#pragma unroll 2
    for (int k0 = 0; k0 < 512; k0 += 32) {
      bf16x8 af[2], bfr[2];
#pragma unroll
      for (int m = 0; m < 2; ++m)
        af[m] = *(const bf16x8*)(&qh[(size_t)(wm + m * 16 + l15) * 512 + k0 + l4 * 8]);
#pragma unroll
      for (int n = 0; n < 2; ++n)
        bfr[n] = *(const bf16x8*)(&kh[(size_t)(wn + n * 16 + l15) * 512 + k0 + l4 * 8]);
#pragma unroll
      for (int m = 0; m < 2; ++m)
#pragma unroll
        for (int n = 0; n < 2; ++n)
          acc[m][n] = MFMA_16x16x32(af[m], bfr[n], acc[m][n]);
    }
    const float scale = 0.125f;
#pragma unroll
    for (int m = 0; m < 2; ++m)
#pragma unroll
      for (int n = 0; n < 2; ++n)
#pragma unroll
        for (int j = 0; j < 4; ++j)
          S[wm + m * 16 + l4 * 4 + j][wn + n * 16 + l15] = acc[m][n][j] * scale;
  }
  __syncthreads();

  {
    const int r = tid >> 2, seg = (tid & 3) * 16;
    float vals[16];
    float mx = -1e30f;
#pragma unroll
    for (int c = 0; c < 16; ++c) { vals[c] = S[r][seg + c]; mx = fmaxf(mx, vals[c]); }
    mx = fmaxf(mx, __shfl_xor(mx, 1));
    mx = fmaxf(mx, __shfl_xor(mx, 2));
    float sum = 0.f;
#pragma unroll
    for (int c = 0; c < 16; ++c) { vals[c] = __expf(vals[c] - mx); sum += vals[c]; }
    sum += __shfl_xor(sum, 1);
    sum += __shfl_xor(sum, 2);
    const float inv = 1.0f / sum;
    bf16_t pr[16];
#pragma unroll
    for (int c = 0; c < 16; ++c) pr[c] = (bf16_t)(vals[c] * inv);
    *(uint4*)(&P[r][seg]) = *(uint4*)(pr);
    *(uint4*)(&P[r][seg + 8]) = *(uint4*)(pr + 8);
  }
  __syncthreads();

  {
    const bf16_t* av = wvT + (size_t)hh * 512 * 64;
    bf16_t* ob = wveffT + (size_t)b * 262144 + (size_t)hh * 64;
    const int wm = (wave >> 1) * 64, wn = (wave & 1) * 32;
    for (int cm0 = 0; cm0 < 512; cm0 += 128) {
      f32x4 acc[4][2] = {};
#pragma unroll
      for (int ks = 0; ks < 2; ++ks) {
        const int k0 = ks * 32;
        bf16x8 af[4], bfr[2];
#pragma unroll
        for (int m = 0; m < 4; ++m)
          af[m] = *(const bf16x8*)(&av[(size_t)(cm0 + wm + m * 16 + l15) * 64 + k0 + l4 * 8]);
#pragma unroll
        for (int n = 0; n < 2; ++n)
          bfr[n] = *(const bf16x8*)(&P[wn + n * 16 + l15][k0 + l4 * 8]);
#pragma unroll
        for (int m = 0; m < 4; ++m)
#pragma unroll
          for (int n = 0; n < 2; ++n)
            acc[m][n] = MFMA_16x16x32(af[m], bfr[n], acc[m][n]);
      }
#pragma unroll
      for (int m = 0; m < 4; ++m)
#pragma unroll
        for (int n = 0; n < 2; ++n)
#pragma unroll
          for (int j = 0; j < 4; ++j)
            ob[(size_t)(cm0 + wm + m * 16 + l4 * 4 + j) * 512 + wn + n * 16 + l15] =
                (bf16_t)acc[m][n][j];
    }
  }
}

// ---------- y GEMM from f32 B (round-12 verified): 256x128, in-LDS transpose staging ----------
__global__ __launch_bounds__(512, 2)
void k_yf32(const bf16_t* __restrict__ A, const float* __restrict__ Bf,
            float* __restrict__ C, const float* __restrict__ bias) {
  const int raw = blockIdx.x;              // 512 blocks
  const int b = raw & 7, c = raw >> 3;     // XCD-affine: xcd = batch
  const int bm = (c & 1) * 256, bn = (c >> 1) * 128;   // M=512, N=4096
  A  += (size_t)b * 262144;
  Bf += (size_t)b * 512 * 4096;
  C  += (size_t)b * 512 * 4096;

  const int tid = threadIdx.x;
  const int wave = tid >> 6, lane = tid & 63;
  const int l15 = lane & 15, l4 = lane >> 4;
  const int wm = (wave >> 1) * 64, wn = (wave & 1) * 64;
  const int rsw = (l15 >> 1) & 3;

  __shared__ bf16_t As[2][256 * 32];   // 32 KB
  __shared__ bf16_t Bs[2][128 * 32];   // 16 KB
  __shared__ float  Ft[32 * 128];      // 16 KB

  f32x4 acc[4][4] = {};

  const int lrow = lane >> 2;
  const int lch = (lane & 3) ^ ((lane >> 3) & 3);
  const bf16_t* srcA = A + (size_t)(bm + wave * 32 + lrow) * 512 + lch * 8;
  bf16_t* dstA = &As[0][wave * 32 * 32];
  const int bufA = 256 * 32;

  const int fr = tid >> 4, fc = (tid & 15) * 8;
  const float* srcB = Bf + (size_t)fr * 4096 + bn + fc;

  const int tn = tid >> 2, tc = (tid & 3) * 8;
  const int wchunk = ((tid & 3) ^ ((tn >> 1) & 3)) * 8;

  float4 rb0 = *(const float4*)(srcB);
  float4 rb1 = *(const float4*)(srcB + 4);
  gload_lds16(srcA, dstA);
  gload_lds16(srcA + 16 * 512, dstA + 512);
  __syncthreads();

  int cur = 0;
  for (int i = 0; i < 16; ++i) {
    *(float4*)(&Ft[fr * 128 + fc]) = rb0;
    *(float4*)(&Ft[fr * 128 + fc + 4]) = rb1;
    __syncthreads();
    {
      bf16_t tb[8];
#pragma unroll
      for (int q = 0; q < 8; ++q) tb[q] = (bf16_t)Ft[(tc + q) * 128 + tn];
      *(uint4*)(&Bs[cur][tn * 32 + wchunk]) = *(uint4*)tb;
    }
    __syncthreads();
    if (i + 1 < 16) {
      const float* nb = srcB + (size_t)(i + 1) * 32 * 4096;
      rb0 = *(const float4*)(nb);
      rb1 = *(const float4*)(nb + 4);
      gload_lds16(srcA + (i + 1) * 32,            dstA + (cur ^ 1) * bufA);
      gload_lds16(srcA + 16 * 512 + (i + 1) * 32, dstA + (cur ^ 1) * bufA + 512);
    }
    bf16x8 af[4], bfr[4];
#pragma unroll
    for (int n = 0; n < 4; ++n)
      bfr[n] = *(const bf16x8*)(&Bs[cur][(wn + n * 16 + l15) * 32 + ((l4 ^ rsw) * 8)]);
#pragma unroll
    for (int m = 0; m < 4; ++m)
      af[m] = *(const bf16x8*)(&As[cur][(wm + m * 16 + l15) * 32 + ((l4 ^ rsw) * 8)]);
#pragma unroll
    for (int m = 0; m < 4; ++m)
#pragma unroll
      for (int n = 0; n < 4; ++n)
        acc[m][n] = MFMA_16x16x32(af[m], bfr[n], acc[m][n]);
    cur ^= 1;
  }

#pragma unroll
  for (int m = 0; m < 4; ++m) {
    const int row0 = bm + wm + m * 16 + l4 * 4;
#pragma unroll
    for (int n = 0; n < 4; ++n) {
      const int col = bn + wn + n * 16 + l15;
#pragma unroll
      for (int j = 0; j < 4; ++j)
        C[(size_t)(row0 + j) * 4096 + col] = acc[m][n][j] + bias[row0 + j];
    }
  }
}

extern "C" void kernel_launch(void* const* d_in, const int* in_sizes, int n_in,
                              void* d_out, int out_size, void* d_ws, size_t ws_size,
                              hipStream_t stream) {
  const float* f_m  = (const float*)d_in[0];
  const float* f_n  = (const float*)d_in[1];
  const float* Wq   = (const float*)d_in[2];
  const float* Wkv  = (const float*)d_in[3];
  const float* Wout = (const float*)d_in[4];
  const float* bout = (const float*)d_in[5];
  float* y = (float*)d_out;

  const size_t SQ  = (size_t)512 * 512;
  char* p = (char*)d_ws;
  bf16_t* wq_b    = (bf16_t*)p; p += SQ * 2;
  bf16_t* wk_b    = (bf16_t*)p; p += SQ * 2;
  bf16_t* wout_b  = (bf16_t*)p; p += SQ * 2;
  bf16_t* wvT     = (bf16_t*)p; p += SQ * 2;               // [h][c][64]
  bf16_t* Hb      = (bf16_t*)p; p += (size_t)8 * SQ * 2;   // [b][c'][c]
  bf16_t* T1      = (bf16_t*)p; p += (size_t)8 * SQ * 2;   // [b][hi][c']
  bf16_t* wveffT  = (bf16_t*)p; p += (size_t)8 * SQ * 2;   // [b][c][hi]
  bf16_t* W2      = (bf16_t*)p; p += (size_t)8 * SQ * 2;   // [b][o][c]
  bf16_t* Hp8     = (bf16_t*)p; p += (size_t)64 * SQ * 2;  // bf16 split-8 partials

  // gram standalone, 2-deep register prefetch
  k_gram256<<<dim3(256), 512, 0, stream>>>(f_n, f_m, Hp8);
  // reduce8 + weight cvt + Wv transpose in one grid
  k_reduce_prep<<<dim3(2048), 256, 0, stream>>>(Hp8, Hb, Wq, Wkv, Wout,
                                                wq_b, wk_b, wout_b, wvT);

  // T1[b][hi][c'] = sum_c Wq[hi][c] H[b][c'][c]
  k_gemm_bt<<<dim3(4, 4, 8), 256, 0, stream>>>(wq_b, Hb, T1, 512, 512, 512,
                                               0, (long long)SQ, (long long)SQ);
  // dots + softmax + wveff fused
  k_dots_wveff<<<dim3(64), 256, 0, stream>>>(T1, wk_b, wvT, wveffT);
  // W2[b][o][c] = sum_hi Wout[o][hi] WvEffT[b][c][hi]
  k_gemm_bt<<<dim3(4, 4, 8), 256, 0, stream>>>(wout_b, wveffT, W2, 512, 512, 512,
                                               0, (long long)SQ, (long long)SQ);
  // y from f32 f_n directly (in-LDS transpose staging), 256x128 tiles
  k_yf32<<<dim3(512), 512, 0, stream>>>(W2, f_n, y, bout);
}